// Round 1
// baseline (4567.811 us; speedup 1.0000x reference)
//
#include <hip/hip_runtime.h>
#include <math.h>

#define EPS_OT 0.05f
#define INV_EPS 20.0f

// ---------------- GEMM: Y[M,512] = X[M,512] @ W[512,512]^T + bias ----------------
__global__ __launch_bounds__(256) void gemm_xwT(const float* __restrict__ X,
                                                const float* __restrict__ W,
                                                const float* __restrict__ bias,
                                                float* __restrict__ Y, int M) {
  __shared__ alignas(16) float Xs[16][68];
  __shared__ alignas(16) float Ws[16][68];
  const int tid = threadIdx.x;
  const int tx = tid & 15, ty = tid >> 4;
  const int lm = tid >> 2, lk = (tid & 3) << 2;
  const int m0 = blockIdx.x << 6, n0 = blockIdx.y << 6;
  const float* Xp = X + (size_t)(m0 + lm) * 512 + lk;
  const float* Wp = W + (size_t)(n0 + lm) * 512 + lk;
  float acc[4][4] = {};
  for (int k0 = 0; k0 < 512; k0 += 16) {
    float4 xv = *(const float4*)(Xp + k0);
    float4 wv = *(const float4*)(Wp + k0);
    __syncthreads();
    Xs[lk + 0][lm] = xv.x; Xs[lk + 1][lm] = xv.y; Xs[lk + 2][lm] = xv.z; Xs[lk + 3][lm] = xv.w;
    Ws[lk + 0][lm] = wv.x; Ws[lk + 1][lm] = wv.y; Ws[lk + 2][lm] = wv.z; Ws[lk + 3][lm] = wv.w;
    __syncthreads();
#pragma unroll
    for (int kk = 0; kk < 16; ++kk) {
      float4 av = *(const float4*)&Xs[kk][ty << 2];
      float4 bv = *(const float4*)&Ws[kk][tx << 2];
      float ar[4] = {av.x, av.y, av.z, av.w};
      float br[4] = {bv.x, bv.y, bv.z, bv.w};
#pragma unroll
      for (int a = 0; a < 4; ++a)
#pragma unroll
        for (int b = 0; b < 4; ++b) acc[a][b] = fmaf(ar[a], br[b], acc[a][b]);
    }
  }
  float4 bb = *(const float4*)&bias[n0 + (tx << 2)];
#pragma unroll
  for (int a = 0; a < 4; ++a) {
    float4 o;
    o.x = acc[a][0] + bb.x; o.y = acc[a][1] + bb.y;
    o.z = acc[a][2] + bb.z; o.w = acc[a][3] + bb.w;
    *(float4*)&Y[(size_t)(m0 + (ty << 2) + a) * 512 + n0 + (tx << 2)] = o;
  }
}

// ------------- per-head l2norm + relayout [B,Nn,H,64] -> [B,H,Nn,64] -------------
__global__ __launch_bounds__(256) void headnorm_k(const float* __restrict__ in,
                                                  float* __restrict__ out,
                                                  int Nn, int do_norm) {
  const int wv = threadIdx.x >> 6, l = threadIdx.x & 63;
  const int chunk = (blockIdx.x << 2) + wv;  // = (b*Nn + n)*8 + h
  const int h = chunk & 7;
  const int bn = chunk >> 3;  // b*Nn + n
  const int n = bn % Nn, b = bn / Nn;
  float x = in[((size_t)bn << 9) + (h << 6) + l];
  float inv = 1.0f;
  if (do_norm) {
    float s = x * x;
#pragma unroll
    for (int off = 32; off; off >>= 1) s += __shfl_xor(s, off, 64);
    inv = 1.0f / fmaxf(sqrtf(s), 1e-12f);
  }
  out[((size_t)(b * 8 + h) * Nn + n) * 64 + l] = x * inv;
}

// ---------- sim = q·k per head; store E = exp((sim-1)/eps)  [128][256][576] ----------
__global__ __launch_bounds__(256) void simE_k(const float* __restrict__ qn,
                                              const float* __restrict__ kn,
                                              float* __restrict__ E) {
  const int s = blockIdx.x, i0 = blockIdx.y << 6, j0 = blockIdx.z << 6;
  __shared__ alignas(16) float Qs[16][68];
  __shared__ alignas(16) float Ks[16][68];
  const int tid = threadIdx.x;
  const int tx = tid & 15, ty = tid >> 4;
  const int lm = tid >> 2, lk = (tid & 3) << 2;
  const float* Qp = qn + ((size_t)s * 256 + i0 + lm) * 64 + lk;
  const float* Kp = kn + ((size_t)s * 576 + j0 + lm) * 64 + lk;
  float acc[4][4] = {};
  for (int c0 = 0; c0 < 64; c0 += 16) {
    float4 qv = *(const float4*)(Qp + c0);
    float4 kv = *(const float4*)(Kp + c0);
    __syncthreads();
    Qs[lk + 0][lm] = qv.x; Qs[lk + 1][lm] = qv.y; Qs[lk + 2][lm] = qv.z; Qs[lk + 3][lm] = qv.w;
    Ks[lk + 0][lm] = kv.x; Ks[lk + 1][lm] = kv.y; Ks[lk + 2][lm] = kv.z; Ks[lk + 3][lm] = kv.w;
    __syncthreads();
#pragma unroll
    for (int kk = 0; kk < 16; ++kk) {
      float4 av = *(const float4*)&Qs[kk][ty << 2];
      float4 bv = *(const float4*)&Ks[kk][tx << 2];
      float ar[4] = {av.x, av.y, av.z, av.w};
      float br[4] = {bv.x, bv.y, bv.z, bv.w};
#pragma unroll
      for (int a = 0; a < 4; ++a)
#pragma unroll
        for (int b = 0; b < 4; ++b) acc[a][b] = fmaf(ar[a], br[b], acc[a][b]);
    }
  }
  float* Ep = E + (size_t)s * 147456;
#pragma unroll
  for (int a = 0; a < 4; ++a) {
    float4 o;
    o.x = __expf((acc[a][0] - 1.0f) * INV_EPS);
    o.y = __expf((acc[a][1] - 1.0f) * INV_EPS);
    o.z = __expf((acc[a][2] - 1.0f) * INV_EPS);
    o.w = __expf((acc[a][3] - 1.0f) * INV_EPS);
    *(float4*)&Ep[(size_t)(i0 + (ty << 2) + a) * 576 + j0 + (tx << 2)] = o;
  }
}

// ------------------------------ Sinkhorn, 100 iters ------------------------------
// One workgroup (1024 thr = 16 waves) per (b,h) slice. Wave w owns rows 16w..16w+15.
// Lane l owns column chunks 4l..4l+3, 256+4l.., (l<16: 512+4l..). Single sweep of E
// per iteration produces both row sums (shuffle-reduce) and col sums (reg + LDS).
__global__ __launch_bounds__(1024) void sinkhorn_k(const float* __restrict__ E,
                                                   float* __restrict__ gA,
                                                   float* __restrict__ gB,
                                                   float C_mu, float C_nu) {
  const int s = blockIdx.x;
  const float* Es = E + (size_t)s * 147456;
  __shared__ alignas(16) float u[256];
  __shared__ alignas(16) float v[576];
  __shared__ alignas(16) float au[256];
  __shared__ alignas(16) float bv[576];
  __shared__ alignas(16) float rsum[256];
  __shared__ alignas(16) float colpart[16][580];
  __shared__ float sSu, sSv;
  const int tid = threadIdx.x;
  const int w = tid >> 6, l = tid & 63;
  const bool m2 = (l < 16);
  if (tid < 256) u[tid] = 0.0f;
  if (tid < 576) v[tid] = 0.0f;
  __syncthreads();
  for (int it = 0; it < 100; ++it) {
    if (w == 0) {
      float m = fmaxf(fmaxf(u[l], u[l + 64]), fmaxf(u[l + 128], u[l + 192]));
#pragma unroll
      for (int off = 32; off; off >>= 1) m = fmaxf(m, __shfl_xor(m, off, 64));
      if (l == 0) sSu = m;
    } else if (w == 1) {
      float m = v[l];
#pragma unroll
      for (int q = 1; q < 9; ++q) m = fmaxf(m, v[l + 64 * q]);
#pragma unroll
      for (int off = 32; off; off >>= 1) m = fmaxf(m, __shfl_xor(m, off, 64));
      if (l == 0) sSv = m;
    }
    __syncthreads();
    const float Su = sSu, Sv = sSv;
    if (tid < 256) au[tid] = __expf((u[tid] - Su) * INV_EPS);
    if (tid < 576) bv[tid] = __expf((v[tid] - Sv) * INV_EPS);
    __syncthreads();
    float4 bv0 = *(const float4*)&bv[4 * l];
    float4 bv1 = *(const float4*)&bv[256 + 4 * l];
    float4 bv2 = make_float4(0.f, 0.f, 0.f, 0.f);
    if (m2) bv2 = *(const float4*)&bv[512 + 4 * l];
    float4 c0 = make_float4(0.f, 0.f, 0.f, 0.f);
    float4 c1 = make_float4(0.f, 0.f, 0.f, 0.f);
    float4 c2 = make_float4(0.f, 0.f, 0.f, 0.f);
    const int i0 = w << 4;
    const float* base = Es + (size_t)i0 * 576;
    for (int r = 0; r < 16; ++r) {
      const float ai = au[i0 + r];
      const float* rp = base + (size_t)r * 576;
      float4 e0 = *(const float4*)(rp + 4 * l);
      float4 e1 = *(const float4*)(rp + 256 + 4 * l);
      float racc;
      racc = e0.x * bv0.x + e0.y * bv0.y + e0.z * bv0.z + e0.w * bv0.w;
      racc += e1.x * bv1.x + e1.y * bv1.y + e1.z * bv1.z + e1.w * bv1.w;
      c0.x = fmaf(e0.x, ai, c0.x); c0.y = fmaf(e0.y, ai, c0.y);
      c0.z = fmaf(e0.z, ai, c0.z); c0.w = fmaf(e0.w, ai, c0.w);
      c1.x = fmaf(e1.x, ai, c1.x); c1.y = fmaf(e1.y, ai, c1.y);
      c1.z = fmaf(e1.z, ai, c1.z); c1.w = fmaf(e1.w, ai, c1.w);
      if (m2) {
        float4 e2 = *(const float4*)(rp + 512 + 4 * l);
        racc += e2.x * bv2.x + e2.y * bv2.y + e2.z * bv2.z + e2.w * bv2.w;
        c2.x = fmaf(e2.x, ai, c2.x); c2.y = fmaf(e2.y, ai, c2.y);
        c2.z = fmaf(e2.z, ai, c2.z); c2.w = fmaf(e2.w, ai, c2.w);
      }
#pragma unroll
      for (int off = 32; off; off >>= 1) racc += __shfl_xor(racc, off, 64);
      if (l == 0) rsum[i0 + r] = racc;
    }
    *(float4*)&colpart[w][4 * l] = c0;
    *(float4*)&colpart[w][256 + 4 * l] = c1;
    if (m2) *(float4*)&colpart[w][512 + 4 * l] = c2;
    __syncthreads();
    if (tid < 256) {
      u[tid] = C_mu - Sv - EPS_OT * __logf(rsum[tid]);
    } else if (tid < 832) {
      const int j = tid - 256;
      float cs = 0.0f;
#pragma unroll
      for (int ww = 0; ww < 16; ++ww) cs += colpart[ww][j];
      v[j] = C_nu - Su - EPS_OT * __logf(cs);
    }
    __syncthreads();
  }
  // score_ij = (1 + eps*lnE)*exp(lnE + gA_i + gB_j); exponent = ln(N1*N2*T) <= ~12, safe.
  if (tid < 256) gA[(size_t)s * 256 + tid] = u[tid] * INV_EPS;
  if (tid < 576) gB[(size_t)s * 576 + tid] = v[tid] * INV_EPS + 11.9012851f;  // ln(147456)
}

// --------------- out[b,i,h*64+c] = sum_j score(i,j) * V[j,c], per slice ---------------
__global__ __launch_bounds__(256) void scorev_k(const float* __restrict__ E,
                                                const float* __restrict__ V,
                                                const float* __restrict__ gA,
                                                const float* __restrict__ gB,
                                                float* __restrict__ Y) {
  const int s = blockIdx.x, i0 = blockIdx.y << 6;
  __shared__ alignas(16) float Ps[16][68];
  __shared__ alignas(16) float Vs[16][68];
  __shared__ float gBl[576];
  __shared__ float gAs[64];
  const int tid = threadIdx.x;
  const int tx = tid & 15, ty = tid >> 4;
  const int lm = tid >> 2, lk = (tid & 3) << 2;
  for (int t = tid; t < 576; t += 256) gBl[t] = gB[(size_t)s * 576 + t];
  if (tid < 64) gAs[tid] = gA[(size_t)s * 256 + i0 + tid];
  const float* Ep = E + (size_t)s * 147456 + (size_t)(i0 + lm) * 576;
  const float* Vp = V + (size_t)s * 576 * 64;
  float acc[4][4] = {};
  __syncthreads();
  for (int j0 = 0; j0 < 576; j0 += 16) {
    float4 e4 = *(const float4*)(Ep + j0 + lk);
    float4 v4 = *(const float4*)(Vp + (size_t)(j0 + ty) * 64 + (tx << 2));
    const float ga = gAs[lm];
    __syncthreads();
    {
      float le, p;
      le = __logf(e4.x); p = __expf(le + ga + gBl[j0 + lk + 0]); Ps[lk + 0][lm] = (1.0f + EPS_OT * le) * p;
      le = __logf(e4.y); p = __expf(le + ga + gBl[j0 + lk + 1]); Ps[lk + 1][lm] = (1.0f + EPS_OT * le) * p;
      le = __logf(e4.z); p = __expf(le + ga + gBl[j0 + lk + 2]); Ps[lk + 2][lm] = (1.0f + EPS_OT * le) * p;
      le = __logf(e4.w); p = __expf(le + ga + gBl[j0 + lk + 3]); Ps[lk + 3][lm] = (1.0f + EPS_OT * le) * p;
    }
    *(float4*)&Vs[ty][tx << 2] = v4;
    __syncthreads();
#pragma unroll
    for (int kk = 0; kk < 16; ++kk) {
      float4 av = *(const float4*)&Ps[kk][ty << 2];
      float4 bvv = *(const float4*)&Vs[kk][tx << 2];
      float ar[4] = {av.x, av.y, av.z, av.w};
      float br[4] = {bvv.x, bvv.y, bvv.z, bvv.w};
#pragma unroll
      for (int a = 0; a < 4; ++a)
#pragma unroll
        for (int b = 0; b < 4; ++b) acc[a][b] = fmaf(ar[a], br[b], acc[a][b]);
    }
  }
  const int b = s >> 3, h = s & 7;
#pragma unroll
  for (int a = 0; a < 4; ++a) {
    float4 o = {acc[a][0], acc[a][1], acc[a][2], acc[a][3]};
    *(float4*)&Y[((size_t)(b * 256 + i0 + (ty << 2) + a) << 9) + (h << 6) + (tx << 2)] = o;
  }
}

// ------------------------- final row l2norm (plain division) -------------------------
__global__ __launch_bounds__(256) void rownorm_k(const float* __restrict__ X,
                                                 float* __restrict__ out) {
  const size_t row = blockIdx.x;
  const int tid = threadIdx.x;
  float x0 = X[(row << 9) + tid], x1 = X[(row << 9) + 256 + tid];
  float st = fmaf(x0, x0, x1 * x1);
#pragma unroll
  for (int off = 32; off; off >>= 1) st += __shfl_xor(st, off, 64);
  __shared__ float ps[4];
  if ((tid & 63) == 0) ps[tid >> 6] = st;
  __syncthreads();
  const float inv = 1.0f / sqrtf(ps[0] + ps[1] + ps[2] + ps[3]);
  out[(row << 9) + tid] = x0 * inv;
  out[(row << 9) + 256 + tid] = x1 * inv;
}

extern "C" void kernel_launch(void* const* d_in, const int* in_sizes, int n_in,
                              void* d_out, int out_size, void* d_ws, size_t ws_size,
                              hipStream_t stream) {
  const float* F_t = (const float*)d_in[0];
  const float* F_s = (const float*)d_in[1];
  const float* Wq = (const float*)d_in[2];
  const float* bq = (const float*)d_in[3];
  const float* Wk = (const float*)d_in[4];
  const float* bk = (const float*)d_in[5];
  const float* Wv = (const float*)d_in[6];
  const float* bvb = (const float*)d_in[7];
  const float* Wp = (const float*)d_in[8];
  const float* bp = (const float*)d_in[9];
  float* out = (float*)d_out;
  float* ws = (float*)d_ws;

  float* T0 = ws;                  // 4,718,592 floats (max-M GEMM out / concat buffer)
  float* T1 = T0 + 4718592;        // 2,097,152
  float* qn = T1 + 2097152;        // 2,097,152  [B,H,256,64]
  float* kn = qn + 2097152;        // 4,718,592  [B,H,576,64]
  float* vn = kn + 4718592;        // 4,718,592  [B,H,576,64]
  float* E  = vn + 4718592;        // 18,874,368 [128,256,576]
  float* gA = E + 18874368;        // 32,768
  float* gB = gA + 32768;          // 73,728  (total ~149.3 MB)

  const float C_mu = (float)(0.05 * log(1.0 / 256.0 + 1e-8));
  const float C_nu = (float)(0.05 * log(1.0 / 576.0 + 1e-8));

  gemm_xwT<<<dim3(64, 8), 256, 0, stream>>>(F_t, Wq, bq, T0, 4096);
  headnorm_k<<<8192, 256, 0, stream>>>(T0, qn, 256, 1);
  gemm_xwT<<<dim3(144, 8), 256, 0, stream>>>(F_s, Wk, bk, T0, 9216);
  headnorm_k<<<18432, 256, 0, stream>>>(T0, kn, 576, 1);
  gemm_xwT<<<dim3(144, 8), 256, 0, stream>>>(F_s, Wv, bvb, T0, 9216);
  headnorm_k<<<18432, 256, 0, stream>>>(T0, vn, 576, 0);
  simE_k<<<dim3(128, 4, 9), 256, 0, stream>>>(qn, kn, E);
  sinkhorn_k<<<128, 1024, 0, stream>>>(E, gA, gB, C_mu, C_nu);
  scorev_k<<<dim3(128, 4), 256, 0, stream>>>(E, vn, gA, gB, T0);
  gemm_xwT<<<dim3(64, 8), 256, 0, stream>>>(T0, Wp, bp, T1, 4096);
  rownorm_k<<<4096, 256, 0, stream>>>(T1, out);
}

// Round 2
// 3021.082 us; speedup vs baseline: 1.5120x; 1.5120x over previous
//
#include <hip/hip_runtime.h>
#include <math.h>

#define EPS_OT 0.05f
#define INV_EPS 20.0f

// ---------------- GEMM: Y[M,512] = X[M,512] @ W[512,512]^T + bias ----------------
__global__ __launch_bounds__(256) void gemm_xwT(const float* __restrict__ X,
                                                const float* __restrict__ W,
                                                const float* __restrict__ bias,
                                                float* __restrict__ Y, int M) {
  __shared__ alignas(16) float Xs[16][68];
  __shared__ alignas(16) float Ws[16][68];
  const int tid = threadIdx.x;
  const int tx = tid & 15, ty = tid >> 4;
  const int lm = tid >> 2, lk = (tid & 3) << 2;
  const int m0 = blockIdx.x << 6, n0 = blockIdx.y << 6;
  const float* Xp = X + (size_t)(m0 + lm) * 512 + lk;
  const float* Wp = W + (size_t)(n0 + lm) * 512 + lk;
  float acc[4][4] = {};
  for (int k0 = 0; k0 < 512; k0 += 16) {
    float4 xv = *(const float4*)(Xp + k0);
    float4 wv = *(const float4*)(Wp + k0);
    __syncthreads();
    Xs[lk + 0][lm] = xv.x; Xs[lk + 1][lm] = xv.y; Xs[lk + 2][lm] = xv.z; Xs[lk + 3][lm] = xv.w;
    Ws[lk + 0][lm] = wv.x; Ws[lk + 1][lm] = wv.y; Ws[lk + 2][lm] = wv.z; Ws[lk + 3][lm] = wv.w;
    __syncthreads();
#pragma unroll
    for (int kk = 0; kk < 16; ++kk) {
      float4 av = *(const float4*)&Xs[kk][ty << 2];
      float4 bv = *(const float4*)&Ws[kk][tx << 2];
      float ar[4] = {av.x, av.y, av.z, av.w};
      float br[4] = {bv.x, bv.y, bv.z, bv.w};
#pragma unroll
      for (int a = 0; a < 4; ++a)
#pragma unroll
        for (int b = 0; b < 4; ++b) acc[a][b] = fmaf(ar[a], br[b], acc[a][b]);
    }
  }
  float4 bb = *(const float4*)&bias[n0 + (tx << 2)];
#pragma unroll
  for (int a = 0; a < 4; ++a) {
    float4 o;
    o.x = acc[a][0] + bb.x; o.y = acc[a][1] + bb.y;
    o.z = acc[a][2] + bb.z; o.w = acc[a][3] + bb.w;
    *(float4*)&Y[(size_t)(m0 + (ty << 2) + a) * 512 + n0 + (tx << 2)] = o;
  }
}

// ------------- per-head l2norm + relayout [B,Nn,H,64] -> [B,H,Nn,64] -------------
__global__ __launch_bounds__(256) void headnorm_k(const float* __restrict__ in,
                                                  float* __restrict__ out,
                                                  int Nn, int do_norm) {
  const int wv = threadIdx.x >> 6, l = threadIdx.x & 63;
  const int chunk = (blockIdx.x << 2) + wv;  // = (b*Nn + n)*8 + h
  const int h = chunk & 7;
  const int bn = chunk >> 3;  // b*Nn + n
  const int n = bn % Nn, b = bn / Nn;
  float x = in[((size_t)bn << 9) + (h << 6) + l];
  float inv = 1.0f;
  if (do_norm) {
    float s = x * x;
#pragma unroll
    for (int off = 32; off; off >>= 1) s += __shfl_xor(s, off, 64);
    inv = 1.0f / fmaxf(sqrtf(s), 1e-12f);
  }
  out[((size_t)(b * 8 + h) * Nn + n) * 64 + l] = x * inv;
}

// ---------- sim = q·k per head; store E = exp((sim-1)/eps)  [128][256][576] ----------
__global__ __launch_bounds__(256) void simE_k(const float* __restrict__ qn,
                                              const float* __restrict__ kn,
                                              float* __restrict__ E) {
  const int s = blockIdx.x, i0 = blockIdx.y << 6, j0 = blockIdx.z << 6;
  __shared__ alignas(16) float Qs[16][68];
  __shared__ alignas(16) float Ks[16][68];
  const int tid = threadIdx.x;
  const int tx = tid & 15, ty = tid >> 4;
  const int lm = tid >> 2, lk = (tid & 3) << 2;
  const float* Qp = qn + ((size_t)s * 256 + i0 + lm) * 64 + lk;
  const float* Kp = kn + ((size_t)s * 576 + j0 + lm) * 64 + lk;
  float acc[4][4] = {};
  for (int c0 = 0; c0 < 64; c0 += 16) {
    float4 qv = *(const float4*)(Qp + c0);
    float4 kv = *(const float4*)(Kp + c0);
    __syncthreads();
    Qs[lk + 0][lm] = qv.x; Qs[lk + 1][lm] = qv.y; Qs[lk + 2][lm] = qv.z; Qs[lk + 3][lm] = qv.w;
    Ks[lk + 0][lm] = kv.x; Ks[lk + 1][lm] = kv.y; Ks[lk + 2][lm] = kv.z; Ks[lk + 3][lm] = kv.w;
    __syncthreads();
#pragma unroll
    for (int kk = 0; kk < 16; ++kk) {
      float4 av = *(const float4*)&Qs[kk][ty << 2];
      float4 bv = *(const float4*)&Ks[kk][tx << 2];
      float ar[4] = {av.x, av.y, av.z, av.w};
      float br[4] = {bv.x, bv.y, bv.z, bv.w};
#pragma unroll
      for (int a = 0; a < 4; ++a)
#pragma unroll
        for (int b = 0; b < 4; ++b) acc[a][b] = fmaf(ar[a], br[b], acc[a][b]);
    }
  }
  float* Ep = E + (size_t)s * 147456;
#pragma unroll
  for (int a = 0; a < 4; ++a) {
    float4 o;
    o.x = __expf((acc[a][0] - 1.0f) * INV_EPS);
    o.y = __expf((acc[a][1] - 1.0f) * INV_EPS);
    o.z = __expf((acc[a][2] - 1.0f) * INV_EPS);
    o.w = __expf((acc[a][3] - 1.0f) * INV_EPS);
    *(float4*)&Ep[(size_t)(i0 + (ty << 2) + a) * 576 + j0 + (tx << 2)] = o;
  }
}

// ------------------------------ Sinkhorn v2: LDS-resident E ------------------------------
// 2 wgs per (b,h) slice; wg holds its 128x576 half of E as bf16 in 144KB LDS.
// 256 wgs x 1024 thr = 1 wg/CU on all 256 CUs -> all co-resident; 2-wg spin barrier
// exchanges column partial sums (2.3KB) per iteration through global memory.
__device__ __forceinline__ unsigned int f2bf(float f) {  // RNE f32->bf16
  unsigned int u = __float_as_uint(f);
  return (u + 0x7FFFu + ((u >> 16) & 1u)) >> 16;
}
__device__ __forceinline__ float blo(unsigned int u) { return __uint_as_float(u << 16); }
__device__ __forceinline__ float bhi(unsigned int u) { return __uint_as_float(u & 0xFFFF0000u); }

#define SK2_SMEM 163456

__global__ __launch_bounds__(1024, 1) void sinkhorn2_k(const float* __restrict__ E,
                                                       float* __restrict__ gA,
                                                       float* __restrict__ gB,
                                                       float* __restrict__ gpart,
                                                       unsigned int* __restrict__ cnt,
                                                       float C_mu, float C_nu) {
  extern __shared__ char smem[];
  unsigned short* Elds = (unsigned short*)smem;          // 128*576 bf16 = 147456 B
  float* colpart = (float*)(smem + 147456);              // [4][640] = 10240 B
  float* vv  = colpart + 2560;                           // 576
  float* bvs = vv + 576;                                 // 576
  float* au  = bvs + 576;                                // 128
  float* uu  = au + 128;                                 // 128
  float* red = uu + 128;                                 // 32
  const int g = blockIdx.x;
  const int s = g >> 1, rh = g & 1, pg = g ^ 1;
  const int tid = threadIdx.x, w = tid >> 6, l = tid & 63;
  const float* Eg = E + (size_t)s * 147456 + (size_t)rh * 73728;
  float* myPart = gpart + (size_t)g * 1280;
  const float* prPart = gpart + (size_t)pg * 1280;
  unsigned int* cntp = cnt + (size_t)s * 32;

  // ---- stage E half into LDS as bf16 ----
  const float4* Eg4 = (const float4*)Eg;
  for (int idx = tid; idx < 18432; idx += 1024) {
    float4 f = Eg4[idx];
    uint2 pk;
    pk.x = f2bf(f.x) | (f2bf(f.y) << 16);
    pk.y = f2bf(f.z) | (f2bf(f.w) << 16);
    ((uint2*)Elds)[idx] = pk;
  }
  if (tid < 128) uu[tid] = 0.0f;
  if (tid < 576) vv[tid] = 0.0f;
  if (tid < 32) red[tid] = 0.0f;
  __syncthreads();

  const int pj = (tid < 512) ? (9 * (tid >> 3) + (tid & 7)) : (576 + (tid - 512));
  const int r0 = w << 3;

  for (int t = 0; t < 100; ++t) {
    const float Su = red[0], Sv = red[1];
    if (tid < 128) au[tid] = __expf((uu[tid] - Su) * INV_EPS);
    if (tid < 576) bvs[tid] = __expf((vv[tid] - Sv) * INV_EPS);
    for (int i = tid; i < 2560; i += 1024) colpart[i] = 0.0f;
    __syncthreads();

    float bvr[8];
    *(float4*)&bvr[0] = *(const float4*)&bvs[8 * l];
    *(float4*)&bvr[4] = *(const float4*)&bvs[8 * l + 4];
    const float bv8 = bvs[512 + l];
    float ca[8] = {0, 0, 0, 0, 0, 0, 0, 0};
    float cb = 0.0f;
#pragma unroll 2
    for (int rr = 0; rr < 8; ++rr) {
      const int r = r0 + rr;
      const uint4 eu = *(const uint4*)(Elds + r * 576 + (l << 3));
      const unsigned int et = (unsigned int)Elds[r * 576 + 512 + l];
      const float ar = au[r];
      float e0 = blo(eu.x), e1 = bhi(eu.x), e2 = blo(eu.y), e3 = bhi(eu.y);
      float e4 = blo(eu.z), e5 = bhi(eu.z), e6 = blo(eu.w), e7 = bhi(eu.w);
      float e8 = __uint_as_float(et << 16);
      float a01 = fmaf(e1, bvr[1], e0 * bvr[0]);
      float a23 = fmaf(e3, bvr[3], e2 * bvr[2]);
      float a45 = fmaf(e5, bvr[5], e4 * bvr[4]);
      float a67 = fmaf(e7, bvr[7], e6 * bvr[6]);
      float racc = (a01 + a23) + (a45 + a67) + e8 * bv8;
      ca[0] = fmaf(e0, ar, ca[0]); ca[1] = fmaf(e1, ar, ca[1]);
      ca[2] = fmaf(e2, ar, ca[2]); ca[3] = fmaf(e3, ar, ca[3]);
      ca[4] = fmaf(e4, ar, ca[4]); ca[5] = fmaf(e5, ar, ca[5]);
      ca[6] = fmaf(e6, ar, ca[6]); ca[7] = fmaf(e7, ar, ca[7]);
      cb = fmaf(e8, ar, cb);
#pragma unroll
      for (int off = 32; off; off >>= 1) racc += __shfl_xor(racc, off, 64);
      if (l == 0) uu[r] = C_mu - Sv - EPS_OT * __logf(racc);
    }
    // column partials: swizzled (col 8l+k -> 9l+k) => conflict-free ds_add
    float* cp = colpart + (w & 3) * 640;
#pragma unroll
    for (int k = 0; k < 8; ++k) atomicAdd(&cp[9 * l + k], ca[k]);
    atomicAdd(&cp[576 + l], cb);
    __syncthreads();

    // publish: my column partial totals + my u-max
    const int parity = t & 1;
    float csMine = 0.0f;
    if (tid < 576) {
      csMine = colpart[pj] + colpart[640 + pj] + colpart[1280 + pj] + colpart[1920 + pj];
      myPart[parity * 640 + tid] = csMine;
    }
    if (w == 0) {
      float um = fmaxf(uu[l], uu[l + 64]);
#pragma unroll
      for (int off = 32; off; off >>= 1) um = fmaxf(um, __shfl_xor(um, off, 64));
      if (l == 0) { myPart[parity * 640 + 576] = um; red[2] = um; }
    }
    __syncthreads();
    if (tid == 0) {
      __threadfence();
      __hip_atomic_fetch_add(cntp, 1u, __ATOMIC_RELEASE, __HIP_MEMORY_SCOPE_AGENT);
      const unsigned int target = 2u * (unsigned int)(t + 1);
      while (__hip_atomic_load(cntp, __ATOMIC_RELAXED, __HIP_MEMORY_SCOPE_AGENT) < target) {
        __builtin_amdgcn_s_sleep(2);
      }
      __threadfence();
    }
    __syncthreads();

    // v update (both wgs compute identically) + next-iteration shifts
    float vmx = -3.0e38f;
    if (tid < 576) {
      float tot = csMine + prPart[parity * 640 + tid];
      float vn = C_nu - Su - EPS_OT * __logf(tot);
      vv[tid] = vn;
      vmx = vn;
    }
#pragma unroll
    for (int off = 32; off; off >>= 1) vmx = fmaxf(vmx, __shfl_xor(vmx, off, 64));
    if (l == 0) red[8 + w] = vmx;
    __syncthreads();
    if (tid == 0) {
      float sv = red[8];
#pragma unroll
      for (int q = 1; q < 16; ++q) sv = fmaxf(sv, red[8 + q]);
      red[1] = sv;
      red[0] = fmaxf(red[2], prPart[parity * 640 + 576]);
    }
    __syncthreads();
  }
  if (tid < 128) gA[(size_t)s * 256 + rh * 128 + tid] = uu[tid] * INV_EPS;
  if (rh == 0 && tid < 576) gB[(size_t)s * 576 + tid] = vv[tid] * INV_EPS + 11.9012851f;  // +ln(147456)
}

// --------------- out[b,i,h*64+c] = sum_j score(i,j) * V[j,c], per slice ---------------
__global__ __launch_bounds__(256) void scorev_k(const float* __restrict__ E,
                                                const float* __restrict__ V,
                                                const float* __restrict__ gA,
                                                const float* __restrict__ gB,
                                                float* __restrict__ Y) {
  const int s = blockIdx.x, i0 = blockIdx.y << 6;
  __shared__ alignas(16) float Ps[16][68];
  __shared__ alignas(16) float Vs[16][68];
  __shared__ float gBl[576];
  __shared__ float gAs[64];
  const int tid = threadIdx.x;
  const int tx = tid & 15, ty = tid >> 4;
  const int lm = tid >> 2, lk = (tid & 3) << 2;
  for (int t = tid; t < 576; t += 256) gBl[t] = gB[(size_t)s * 576 + t];
  if (tid < 64) gAs[tid] = gA[(size_t)s * 256 + i0 + tid];
  const float* Ep = E + (size_t)s * 147456 + (size_t)(i0 + lm) * 576;
  const float* Vp = V + (size_t)s * 576 * 64;
  float acc[4][4] = {};
  __syncthreads();
  for (int j0 = 0; j0 < 576; j0 += 16) {
    float4 e4 = *(const float4*)(Ep + j0 + lk);
    float4 v4 = *(const float4*)(Vp + (size_t)(j0 + ty) * 64 + (tx << 2));
    const float ga = gAs[lm];
    __syncthreads();
    {
      float le, p;
      le = __logf(e4.x); p = __expf(le + ga + gBl[j0 + lk + 0]); Ps[lk + 0][lm] = (1.0f + EPS_OT * le) * p;
      le = __logf(e4.y); p = __expf(le + ga + gBl[j0 + lk + 1]); Ps[lk + 1][lm] = (1.0f + EPS_OT * le) * p;
      le = __logf(e4.z); p = __expf(le + ga + gBl[j0 + lk + 2]); Ps[lk + 2][lm] = (1.0f + EPS_OT * le) * p;
      le = __logf(e4.w); p = __expf(le + ga + gBl[j0 + lk + 3]); Ps[lk + 3][lm] = (1.0f + EPS_OT * le) * p;
    }
    *(float4*)&Vs[ty][tx << 2] = v4;
    __syncthreads();
#pragma unroll
    for (int kk = 0; kk < 16; ++kk) {
      float4 av = *(const float4*)&Ps[kk][ty << 2];
      float4 bvv = *(const float4*)&Vs[kk][tx << 2];
      float ar[4] = {av.x, av.y, av.z, av.w};
      float br[4] = {bvv.x, bvv.y, bvv.z, bvv.w};
#pragma unroll
      for (int a = 0; a < 4; ++a)
#pragma unroll
        for (int b = 0; b < 4; ++b) acc[a][b] = fmaf(ar[a], br[b], acc[a][b]);
    }
  }
  const int b = s >> 3, h = s & 7;
#pragma unroll
  for (int a = 0; a < 4; ++a) {
    float4 o = {acc[a][0], acc[a][1], acc[a][2], acc[a][3]};
    *(float4*)&Y[((size_t)(b * 256 + i0 + (ty << 2) + a) << 9) + (h << 6) + (tx << 2)] = o;
  }
}

// ------------------------- final row l2norm (plain division) -------------------------
__global__ __launch_bounds__(256) void rownorm_k(const float* __restrict__ X,
                                                 float* __restrict__ out) {
  const size_t row = blockIdx.x;
  const int tid = threadIdx.x;
  float x0 = X[(row << 9) + tid], x1 = X[(row << 9) + 256 + tid];
  float st = fmaf(x0, x0, x1 * x1);
#pragma unroll
  for (int off = 32; off; off >>= 1) st += __shfl_xor(st, off, 64);
  __shared__ float ps[4];
  if ((tid & 63) == 0) ps[tid >> 6] = st;
  __syncthreads();
  const float inv = 1.0f / sqrtf(ps[0] + ps[1] + ps[2] + ps[3]);
  out[(row << 9) + tid] = x0 * inv;
  out[(row << 9) + 256 + tid] = x1 * inv;
}

extern "C" void kernel_launch(void* const* d_in, const int* in_sizes, int n_in,
                              void* d_out, int out_size, void* d_ws, size_t ws_size,
                              hipStream_t stream) {
  const float* F_t = (const float*)d_in[0];
  const float* F_s = (const float*)d_in[1];
  const float* Wq = (const float*)d_in[2];
  const float* bq = (const float*)d_in[3];
  const float* Wk = (const float*)d_in[4];
  const float* bk = (const float*)d_in[5];
  const float* Wv = (const float*)d_in[6];
  const float* bvb = (const float*)d_in[7];
  const float* Wp = (const float*)d_in[8];
  const float* bp = (const float*)d_in[9];
  float* out = (float*)d_out;
  float* ws = (float*)d_ws;

  float* T0 = ws;                  // 4,718,592 floats
  float* T1 = T0 + 4718592;        // 2,097,152 (dead during sinkhorn -> hosts cnt+gpart)
  float* qn = T1 + 2097152;        // 2,097,152  [B,H,256,64]
  float* kn = qn + 2097152;        // 4,718,592  [B,H,576,64]
  float* vn = kn + 4718592;        // 4,718,592  [B,H,576,64]
  float* E  = vn + 4718592;        // 18,874,368 [128,256,576]
  float* gA = E + 18874368;        // 32,768
  float* gB = gA + 32768;          // 73,728

  unsigned int* cnt = (unsigned int*)T1;  // 128 slices * 32-int stride = 16 KB
  float* gpart = T1 + 4096;               // 256 wgs * 2 * 640 floats = 1.31 MB

  const float C_mu = (float)(0.05 * log(1.0 / 256.0 + 1e-8));
  const float C_nu = (float)(0.05 * log(1.0 / 576.0 + 1e-8));

  hipMemsetAsync(cnt, 0, 128 * 32 * sizeof(unsigned int), stream);
  (void)hipFuncSetAttribute((const void*)sinkhorn2_k,
                            hipFuncAttributeMaxDynamicSharedMemorySize, SK2_SMEM);

  gemm_xwT<<<dim3(64, 8), 256, 0, stream>>>(F_t, Wq, bq, T0, 4096);
  headnorm_k<<<8192, 256, 0, stream>>>(T0, qn, 256, 1);
  gemm_xwT<<<dim3(144, 8), 256, 0, stream>>>(F_s, Wk, bk, T0, 9216);
  headnorm_k<<<18432, 256, 0, stream>>>(T0, kn, 576, 1);
  gemm_xwT<<<dim3(144, 8), 256, 0, stream>>>(F_s, Wv, bvb, T0, 9216);
  headnorm_k<<<18432, 256, 0, stream>>>(T0, vn, 576, 0);
  simE_k<<<dim3(128, 4, 9), 256, 0, stream>>>(qn, kn, E);
  sinkhorn2_k<<<256, 1024, SK2_SMEM, stream>>>(E, gA, gB, gpart, cnt, C_mu, C_nu);
  scorev_k<<<dim3(128, 4), 256, 0, stream>>>(E, vn, gA, gB, T0);
  gemm_xwT<<<dim3(64, 8), 256, 0, stream>>>(T0, Wp, bp, T1, 4096);
  rownorm_k<<<4096, 256, 0, stream>>>(T1, out);
}

// Round 3
// 2166.198 us; speedup vs baseline: 2.1087x; 1.3946x over previous
//
#include <hip/hip_runtime.h>
#include <math.h>

#define EPS_OT 0.05f
#define INV_EPS 20.0f

// ---------------- GEMM: Y[M,512] = X[M,512] @ W[512,512]^T + bias ----------------
__global__ __launch_bounds__(256) void gemm_xwT(const float* __restrict__ X,
                                                const float* __restrict__ W,
                                                const float* __restrict__ bias,
                                                float* __restrict__ Y, int M) {
  __shared__ alignas(16) float Xs[16][68];
  __shared__ alignas(16) float Ws[16][68];
  const int tid = threadIdx.x;
  const int tx = tid & 15, ty = tid >> 4;
  const int lm = tid >> 2, lk = (tid & 3) << 2;
  const int m0 = blockIdx.x << 6, n0 = blockIdx.y << 6;
  const float* Xp = X + (size_t)(m0 + lm) * 512 + lk;
  const float* Wp = W + (size_t)(n0 + lm) * 512 + lk;
  float acc[4][4] = {};
  for (int k0 = 0; k0 < 512; k0 += 16) {
    float4 xv = *(const float4*)(Xp + k0);
    float4 wv = *(const float4*)(Wp + k0);
    __syncthreads();
    Xs[lk + 0][lm] = xv.x; Xs[lk + 1][lm] = xv.y; Xs[lk + 2][lm] = xv.z; Xs[lk + 3][lm] = xv.w;
    Ws[lk + 0][lm] = wv.x; Ws[lk + 1][lm] = wv.y; Ws[lk + 2][lm] = wv.z; Ws[lk + 3][lm] = wv.w;
    __syncthreads();
#pragma unroll
    for (int kk = 0; kk < 16; ++kk) {
      float4 av = *(const float4*)&Xs[kk][ty << 2];
      float4 bv = *(const float4*)&Ws[kk][tx << 2];
      float ar[4] = {av.x, av.y, av.z, av.w};
      float br[4] = {bv.x, bv.y, bv.z, bv.w};
#pragma unroll
      for (int a = 0; a < 4; ++a)
#pragma unroll
        for (int b = 0; b < 4; ++b) acc[a][b] = fmaf(ar[a], br[b], acc[a][b]);
    }
  }
  float4 bb = *(const float4*)&bias[n0 + (tx << 2)];
#pragma unroll
  for (int a = 0; a < 4; ++a) {
    float4 o;
    o.x = acc[a][0] + bb.x; o.y = acc[a][1] + bb.y;
    o.z = acc[a][2] + bb.z; o.w = acc[a][3] + bb.w;
    *(float4*)&Y[(size_t)(m0 + (ty << 2) + a) * 512 + n0 + (tx << 2)] = o;
  }
}

// ------------- per-head l2norm + relayout [B,Nn,H,64] -> [B,H,Nn,64] -------------
__global__ __launch_bounds__(256) void headnorm_k(const float* __restrict__ in,
                                                  float* __restrict__ out,
                                                  int Nn, int do_norm) {
  const int wv = threadIdx.x >> 6, l = threadIdx.x & 63;
  const int chunk = (blockIdx.x << 2) + wv;  // = (b*Nn + n)*8 + h
  const int h = chunk & 7;
  const int bn = chunk >> 3;  // b*Nn + n
  const int n = bn % Nn, b = bn / Nn;
  float x = in[((size_t)bn << 9) + (h << 6) + l];
  float inv = 1.0f;
  if (do_norm) {
    float s = x * x;
#pragma unroll
    for (int off = 32; off; off >>= 1) s += __shfl_xor(s, off, 64);
    inv = 1.0f / fmaxf(sqrtf(s), 1e-12f);
  }
  out[((size_t)(b * 8 + h) * Nn + n) * 64 + l] = x * inv;
}

// ---------- sim = q·k per head; store E = exp((sim-1)/eps)  [128][256][576] ----------
__global__ __launch_bounds__(256) void simE_k(const float* __restrict__ qn,
                                              const float* __restrict__ kn,
                                              float* __restrict__ E) {
  const int s = blockIdx.x, i0 = blockIdx.y << 6, j0 = blockIdx.z << 6;
  __shared__ alignas(16) float Qs[16][68];
  __shared__ alignas(16) float Ks[16][68];
  const int tid = threadIdx.x;
  const int tx = tid & 15, ty = tid >> 4;
  const int lm = tid >> 2, lk = (tid & 3) << 2;
  const float* Qp = qn + ((size_t)s * 256 + i0 + lm) * 64 + lk;
  const float* Kp = kn + ((size_t)s * 576 + j0 + lm) * 64 + lk;
  float acc[4][4] = {};
  for (int c0 = 0; c0 < 64; c0 += 16) {
    float4 qv = *(const float4*)(Qp + c0);
    float4 kv = *(const float4*)(Kp + c0);
    __syncthreads();
    Qs[lk + 0][lm] = qv.x; Qs[lk + 1][lm] = qv.y; Qs[lk + 2][lm] = qv.z; Qs[lk + 3][lm] = qv.w;
    Ks[lk + 0][lm] = kv.x; Ks[lk + 1][lm] = kv.y; Ks[lk + 2][lm] = kv.z; Ks[lk + 3][lm] = kv.w;
    __syncthreads();
#pragma unroll
    for (int kk = 0; kk < 16; ++kk) {
      float4 av = *(const float4*)&Qs[kk][ty << 2];
      float4 bv = *(const float4*)&Ks[kk][tx << 2];
      float ar[4] = {av.x, av.y, av.z, av.w};
      float br[4] = {bv.x, bv.y, bv.z, bv.w};
#pragma unroll
      for (int a = 0; a < 4; ++a)
#pragma unroll
        for (int b = 0; b < 4; ++b) acc[a][b] = fmaf(ar[a], br[b], acc[a][b]);
    }
  }
  float* Ep = E + (size_t)s * 147456;
#pragma unroll
  for (int a = 0; a < 4; ++a) {
    float4 o;
    o.x = __expf((acc[a][0] - 1.0f) * INV_EPS);
    o.y = __expf((acc[a][1] - 1.0f) * INV_EPS);
    o.z = __expf((acc[a][2] - 1.0f) * INV_EPS);
    o.w = __expf((acc[a][3] - 1.0f) * INV_EPS);
    *(float4*)&Ep[(size_t)(i0 + (ty << 2) + a) * 576 + j0 + (tx << 2)] = o;
  }
}

// ------------------------------ Sinkhorn v3: LDS-resident E, fence-free sync ------------
// 2 wgs per (b,h) slice; wg holds its 128x576 half of E as bf16 in 144KB LDS.
// Cross-wg exchange via RELAXED agent-scope atomics (sc1 -> performed at MALL, no L2
// flush). Ordering: publish stores -> s_waitcnt(0) -> __syncthreads (each wave drains
// vmcnt before s_barrier) -> relaxed flag add -> partner spin -> __syncthreads -> loads.
// NO __threadfence (device fence = buffer_wbl2/inv full-L2 walk, ~10us each - the R2 stall).
__device__ __forceinline__ unsigned int f2bf(float f) {  // RNE f32->bf16
  unsigned int u = __float_as_uint(f);
  return (u + 0x7FFFu + ((u >> 16) & 1u)) >> 16;
}
__device__ __forceinline__ float blo(unsigned int u) { return __uint_as_float(u << 16); }
__device__ __forceinline__ float bhi(unsigned int u) { return __uint_as_float(u & 0xFFFF0000u); }

#define SK2_SMEM 163456

__global__ __launch_bounds__(1024, 1) void sinkhorn2_k(const float* __restrict__ E,
                                                       float* __restrict__ gA,
                                                       float* __restrict__ gB,
                                                       float* __restrict__ gpart,
                                                       unsigned int* __restrict__ cnt,
                                                       float C_mu, float C_nu) {
  extern __shared__ char smem[];
  unsigned short* Elds = (unsigned short*)smem;          // 128*576 bf16 = 147456 B
  float* colpart = (float*)(smem + 147456);              // [4][640] = 10240 B
  float* vv  = colpart + 2560;                           // 576
  float* bvs = vv + 576;                                 // 576
  float* au  = bvs + 576;                                // 128
  float* uu  = au + 128;                                 // 128
  float* red = uu + 128;                                 // 32
  const int g = blockIdx.x;
  const int s = g >> 1, rh = g & 1, pg = g ^ 1;
  const int tid = threadIdx.x, w = tid >> 6, l = tid & 63;
  const float* Eg = E + (size_t)s * 147456 + (size_t)rh * 73728;
  float* myPart = gpart + (size_t)g * 1280;
  float* prPart = gpart + (size_t)pg * 1280;
  unsigned int* cntp = cnt + (size_t)s * 32;

  // ---- stage E half into LDS as bf16 ----
  const float4* Eg4 = (const float4*)Eg;
  for (int idx = tid; idx < 18432; idx += 1024) {
    float4 f = Eg4[idx];
    uint2 pk;
    pk.x = f2bf(f.x) | (f2bf(f.y) << 16);
    pk.y = f2bf(f.z) | (f2bf(f.w) << 16);
    ((uint2*)Elds)[idx] = pk;
  }
  if (tid < 128) uu[tid] = 0.0f;
  if (tid < 576) vv[tid] = 0.0f;
  if (tid < 32) red[tid] = 0.0f;
  __syncthreads();

  const int pj = (tid < 512) ? (9 * (tid >> 3) + (tid & 7)) : (576 + (tid - 512));
  const int r0 = w << 3;

  for (int t = 0; t < 100; ++t) {
    const float Su = red[0], Sv = red[1];
    if (tid < 128) au[tid] = __expf((uu[tid] - Su) * INV_EPS);
    if (tid < 576) bvs[tid] = __expf((vv[tid] - Sv) * INV_EPS);
    for (int i = tid; i < 2560; i += 1024) colpart[i] = 0.0f;
    __syncthreads();

    float bvr[8];
    *(float4*)&bvr[0] = *(const float4*)&bvs[8 * l];
    *(float4*)&bvr[4] = *(const float4*)&bvs[8 * l + 4];
    const float bv8 = bvs[512 + l];
    float ca[8] = {0, 0, 0, 0, 0, 0, 0, 0};
    float cb = 0.0f;
#pragma unroll 2
    for (int rr = 0; rr < 8; ++rr) {
      const int r = r0 + rr;
      const uint4 eu = *(const uint4*)(Elds + r * 576 + (l << 3));
      const unsigned int et = (unsigned int)Elds[r * 576 + 512 + l];
      const float ar = au[r];
      float e0 = blo(eu.x), e1 = bhi(eu.x), e2 = blo(eu.y), e3 = bhi(eu.y);
      float e4 = blo(eu.z), e5 = bhi(eu.z), e6 = blo(eu.w), e7 = bhi(eu.w);
      float e8 = __uint_as_float(et << 16);
      float a01 = fmaf(e1, bvr[1], e0 * bvr[0]);
      float a23 = fmaf(e3, bvr[3], e2 * bvr[2]);
      float a45 = fmaf(e5, bvr[5], e4 * bvr[4]);
      float a67 = fmaf(e7, bvr[7], e6 * bvr[6]);
      float racc = (a01 + a23) + (a45 + a67) + e8 * bv8;
      ca[0] = fmaf(e0, ar, ca[0]); ca[1] = fmaf(e1, ar, ca[1]);
      ca[2] = fmaf(e2, ar, ca[2]); ca[3] = fmaf(e3, ar, ca[3]);
      ca[4] = fmaf(e4, ar, ca[4]); ca[5] = fmaf(e5, ar, ca[5]);
      ca[6] = fmaf(e6, ar, ca[6]); ca[7] = fmaf(e7, ar, ca[7]);
      cb = fmaf(e8, ar, cb);
#pragma unroll
      for (int off = 32; off; off >>= 1) racc += __shfl_xor(racc, off, 64);
      if (l == 0) uu[r] = C_mu - Sv - EPS_OT * __logf(racc);
    }
    // column partials: swizzled (col 8l+k -> 9l+k) => conflict-free ds_add
    float* cp = colpart + (w & 3) * 640;
#pragma unroll
    for (int k = 0; k < 8; ++k) atomicAdd(&cp[9 * l + k], ca[k]);
    atomicAdd(&cp[576 + l], cb);
    __syncthreads();

    // publish: my column partial totals + my u-max (relaxed agent atomics -> MALL)
    const int parity = t & 1;
    float csMine = 0.0f;
    if (tid < 576) {
      csMine = colpart[pj] + colpart[640 + pj] + colpart[1280 + pj] + colpart[1920 + pj];
      __hip_atomic_store(&myPart[parity * 640 + tid], csMine, __ATOMIC_RELAXED,
                         __HIP_MEMORY_SCOPE_AGENT);
    }
    if (w == 0) {
      float um = fmaxf(uu[l], uu[l + 64]);
#pragma unroll
      for (int off = 32; off; off >>= 1) um = fmaxf(um, __shfl_xor(um, off, 64));
      if (l == 0) {
        __hip_atomic_store(&myPart[parity * 640 + 576], um, __ATOMIC_RELAXED,
                           __HIP_MEMORY_SCOPE_AGENT);
        red[2] = um;
      }
    }
    __builtin_amdgcn_s_waitcnt(0);  // drain this wave's stores (ACK at MALL)
    __syncthreads();                // all waves drained + arrived
    if (tid == 0) {
      __hip_atomic_fetch_add(cntp, 1u, __ATOMIC_RELAXED, __HIP_MEMORY_SCOPE_AGENT);
      const unsigned int target = 2u * (unsigned int)(t + 1);
      while (__hip_atomic_load(cntp, __ATOMIC_RELAXED, __HIP_MEMORY_SCOPE_AGENT) < target) {
        __builtin_amdgcn_s_sleep(2);
      }
    }
    __syncthreads();

    // v update (both wgs compute identically) + next-iteration shifts
    float vmx = -3.0e38f;
    if (tid < 576) {
      float prc = __hip_atomic_load(&prPart[parity * 640 + tid], __ATOMIC_RELAXED,
                                    __HIP_MEMORY_SCOPE_AGENT);
      float tot = csMine + prc;
      float vn = C_nu - Su - EPS_OT * __logf(tot);
      vv[tid] = vn;
      vmx = vn;
    }
#pragma unroll
    for (int off = 32; off; off >>= 1) vmx = fmaxf(vmx, __shfl_xor(vmx, off, 64));
    if (l == 0) red[8 + w] = vmx;
    __syncthreads();
    if (tid == 0) {
      float sv = red[8];
#pragma unroll
      for (int q = 1; q < 16; ++q) sv = fmaxf(sv, red[8 + q]);
      red[1] = sv;
      float pum = __hip_atomic_load(&prPart[parity * 640 + 576], __ATOMIC_RELAXED,
                                    __HIP_MEMORY_SCOPE_AGENT);
      red[0] = fmaxf(red[2], pum);
    }
    __syncthreads();
  }
  if (tid < 128) gA[(size_t)s * 256 + rh * 128 + tid] = uu[tid] * INV_EPS;
  if (rh == 0 && tid < 576) gB[(size_t)s * 576 + tid] = vv[tid] * INV_EPS + 11.9012851f;  // +ln(147456)
}

// --------------- out[b,i,h*64+c] = sum_j score(i,j) * V[j,c], per slice ---------------
__global__ __launch_bounds__(256) void scorev_k(const float* __restrict__ E,
                                                const float* __restrict__ V,
                                                const float* __restrict__ gA,
                                                const float* __restrict__ gB,
                                                float* __restrict__ Y) {
  const int s = blockIdx.x, i0 = blockIdx.y << 6;
  __shared__ alignas(16) float Ps[16][68];
  __shared__ alignas(16) float Vs[16][68];
  __shared__ float gBl[576];
  __shared__ float gAs[64];
  const int tid = threadIdx.x;
  const int tx = tid & 15, ty = tid >> 4;
  const int lm = tid >> 2, lk = (tid & 3) << 2;
  for (int t = tid; t < 576; t += 256) gBl[t] = gB[(size_t)s * 576 + t];
  if (tid < 64) gAs[tid] = gA[(size_t)s * 256 + i0 + tid];
  const float* Ep = E + (size_t)s * 147456 + (size_t)(i0 + lm) * 576;
  const float* Vp = V + (size_t)s * 576 * 64;
  float acc[4][4] = {};
  __syncthreads();
  for (int j0 = 0; j0 < 576; j0 += 16) {
    float4 e4 = *(const float4*)(Ep + j0 + lk);
    float4 v4 = *(const float4*)(Vp + (size_t)(j0 + ty) * 64 + (tx << 2));
    const float ga = gAs[lm];
    __syncthreads();
    {
      float le, p;
      le = __logf(e4.x); p = __expf(le + ga + gBl[j0 + lk + 0]); Ps[lk + 0][lm] = (1.0f + EPS_OT * le) * p;
      le = __logf(e4.y); p = __expf(le + ga + gBl[j0 + lk + 1]); Ps[lk + 1][lm] = (1.0f + EPS_OT * le) * p;
      le = __logf(e4.z); p = __expf(le + ga + gBl[j0 + lk + 2]); Ps[lk + 2][lm] = (1.0f + EPS_OT * le) * p;
      le = __logf(e4.w); p = __expf(le + ga + gBl[j0 + lk + 3]); Ps[lk + 3][lm] = (1.0f + EPS_OT * le) * p;
    }
    *(float4*)&Vs[ty][tx << 2] = v4;
    __syncthreads();
#pragma unroll
    for (int kk = 0; kk < 16; ++kk) {
      float4 av = *(const float4*)&Ps[kk][ty << 2];
      float4 bvv = *(const float4*)&Vs[kk][tx << 2];
      float ar[4] = {av.x, av.y, av.z, av.w};
      float br[4] = {bvv.x, bvv.y, bvv.z, bvv.w};
#pragma unroll
      for (int a = 0; a < 4; ++a)
#pragma unroll
        for (int b = 0; b < 4; ++b) acc[a][b] = fmaf(ar[a], br[b], acc[a][b]);
    }
  }
  const int b = s >> 3, h = s & 7;
#pragma unroll
  for (int a = 0; a < 4; ++a) {
    float4 o = {acc[a][0], acc[a][1], acc[a][2], acc[a][3]};
    *(float4*)&Y[((size_t)(b * 256 + i0 + (ty << 2) + a) << 9) + (h << 6) + (tx << 2)] = o;
  }
}

// ------------------------- final row l2norm (plain division) -------------------------
__global__ __launch_bounds__(256) void rownorm_k(const float* __restrict__ X,
                                                 float* __restrict__ out) {
  const size_t row = blockIdx.x;
  const int tid = threadIdx.x;
  float x0 = X[(row << 9) + tid], x1 = X[(row << 9) + 256 + tid];
  float st = fmaf(x0, x0, x1 * x1);
#pragma unroll
  for (int off = 32; off; off >>= 1) st += __shfl_xor(st, off, 64);
  __shared__ float ps[4];
  if ((tid & 63) == 0) ps[tid >> 6] = st;
  __syncthreads();
  const float inv = 1.0f / sqrtf(ps[0] + ps[1] + ps[2] + ps[3]);
  out[(row << 9) + tid] = x0 * inv;
  out[(row << 9) + 256 + tid] = x1 * inv;
}

extern "C" void kernel_launch(void* const* d_in, const int* in_sizes, int n_in,
                              void* d_out, int out_size, void* d_ws, size_t ws_size,
                              hipStream_t stream) {
  const float* F_t = (const float*)d_in[0];
  const float* F_s = (const float*)d_in[1];
  const float* Wq = (const float*)d_in[2];
  const float* bq = (const float*)d_in[3];
  const float* Wk = (const float*)d_in[4];
  const float* bk = (const float*)d_in[5];
  const float* Wv = (const float*)d_in[6];
  const float* bvb = (const float*)d_in[7];
  const float* Wp = (const float*)d_in[8];
  const float* bp = (const float*)d_in[9];
  float* out = (float*)d_out;
  float* ws = (float*)d_ws;

  float* T0 = ws;                  // 4,718,592 floats
  float* T1 = T0 + 4718592;        // 2,097,152 (dead during sinkhorn -> hosts cnt+gpart)
  float* qn = T1 + 2097152;        // 2,097,152  [B,H,256,64]
  float* kn = qn + 2097152;        // 4,718,592  [B,H,576,64]
  float* vn = kn + 4718592;        // 4,718,592  [B,H,576,64]
  float* E  = vn + 4718592;        // 18,874,368 [128,256,576]
  float* gA = E + 18874368;        // 32,768
  float* gB = gA + 32768;          // 73,728

  unsigned int* cnt = (unsigned int*)T1;  // 128 slices * 32-int stride = 16 KB
  float* gpart = T1 + 4096;               // 256 wgs * 2 * 640 floats = 1.31 MB

  const float C_mu = (float)(0.05 * log(1.0 / 256.0 + 1e-8));
  const float C_nu = (float)(0.05 * log(1.0 / 576.0 + 1e-8));

  hipMemsetAsync(cnt, 0, 128 * 32 * sizeof(unsigned int), stream);
  (void)hipFuncSetAttribute((const void*)sinkhorn2_k,
                            hipFuncAttributeMaxDynamicSharedMemorySize, SK2_SMEM);

  gemm_xwT<<<dim3(64, 8), 256, 0, stream>>>(F_t, Wq, bq, T0, 4096);
  headnorm_k<<<8192, 256, 0, stream>>>(T0, qn, 256, 1);
  gemm_xwT<<<dim3(144, 8), 256, 0, stream>>>(F_s, Wk, bk, T0, 9216);
  headnorm_k<<<18432, 256, 0, stream>>>(T0, kn, 576, 1);
  gemm_xwT<<<dim3(144, 8), 256, 0, stream>>>(F_s, Wv, bvb, T0, 9216);
  headnorm_k<<<18432, 256, 0, stream>>>(T0, vn, 576, 0);
  simE_k<<<dim3(128, 4, 9), 256, 0, stream>>>(qn, kn, E);
  sinkhorn2_k<<<256, 1024, SK2_SMEM, stream>>>(E, gA, gB, gpart, cnt, C_mu, C_nu);
  scorev_k<<<dim3(128, 4), 256, 0, stream>>>(E, vn, gA, gB, T0);
  gemm_xwT<<<dim3(64, 8), 256, 0, stream>>>(T0, Wp, bp, T1, 4096);
  rownorm_k<<<4096, 256, 0, stream>>>(T1, out);
}

// Round 4
// 1060.083 us; speedup vs baseline: 4.3089x; 2.0434x over previous
//
#include <hip/hip_runtime.h>
#include <math.h>

#define EPS_OT 0.05f
#define INV_EPS 20.0f

typedef __attribute__((ext_vector_type(8))) short short8;
typedef __attribute__((ext_vector_type(4))) float f32x4;
union Pk { uint4 u; short8 s; };

// ---------------- GEMM: Y[M,512] = X[M,512] @ W[512,512]^T + bias ----------------
__global__ __launch_bounds__(256) void gemm_xwT(const float* __restrict__ X,
                                                const float* __restrict__ W,
                                                const float* __restrict__ bias,
                                                float* __restrict__ Y, int M) {
  __shared__ alignas(16) float Xs[16][68];
  __shared__ alignas(16) float Ws[16][68];
  const int tid = threadIdx.x;
  const int tx = tid & 15, ty = tid >> 4;
  const int lm = tid >> 2, lk = (tid & 3) << 2;
  const int m0 = blockIdx.x << 6, n0 = blockIdx.y << 6;
  const float* Xp = X + (size_t)(m0 + lm) * 512 + lk;
  const float* Wp = W + (size_t)(n0 + lm) * 512 + lk;
  float acc[4][4] = {};
  for (int k0 = 0; k0 < 512; k0 += 16) {
    float4 xv = *(const float4*)(Xp + k0);
    float4 wv = *(const float4*)(Wp + k0);
    __syncthreads();
    Xs[lk + 0][lm] = xv.x; Xs[lk + 1][lm] = xv.y; Xs[lk + 2][lm] = xv.z; Xs[lk + 3][lm] = xv.w;
    Ws[lk + 0][lm] = wv.x; Ws[lk + 1][lm] = wv.y; Ws[lk + 2][lm] = wv.z; Ws[lk + 3][lm] = wv.w;
    __syncthreads();
#pragma unroll
    for (int kk = 0; kk < 16; ++kk) {
      float4 av = *(const float4*)&Xs[kk][ty << 2];
      float4 bv = *(const float4*)&Ws[kk][tx << 2];
      float ar[4] = {av.x, av.y, av.z, av.w};
      float br[4] = {bv.x, bv.y, bv.z, bv.w};
#pragma unroll
      for (int a = 0; a < 4; ++a)
#pragma unroll
        for (int b = 0; b < 4; ++b) acc[a][b] = fmaf(ar[a], br[b], acc[a][b]);
    }
  }
  float4 bb = *(const float4*)&bias[n0 + (tx << 2)];
#pragma unroll
  for (int a = 0; a < 4; ++a) {
    float4 o;
    o.x = acc[a][0] + bb.x; o.y = acc[a][1] + bb.y;
    o.z = acc[a][2] + bb.z; o.w = acc[a][3] + bb.w;
    *(float4*)&Y[(size_t)(m0 + (ty << 2) + a) * 512 + n0 + (tx << 2)] = o;
  }
}

// ------------- per-head l2norm + relayout [B,Nn,H,64] -> [B,H,Nn,64] -------------
__global__ __launch_bounds__(256) void headnorm_k(const float* __restrict__ in,
                                                  float* __restrict__ out,
                                                  int Nn, int do_norm) {
  const int wv = threadIdx.x >> 6, l = threadIdx.x & 63;
  const int chunk = (blockIdx.x << 2) + wv;  // = (b*Nn + n)*8 + h
  const int h = chunk & 7;
  const int bn = chunk >> 3;  // b*Nn + n
  const int n = bn % Nn, b = bn / Nn;
  float x = in[((size_t)bn << 9) + (h << 6) + l];
  float inv = 1.0f;
  if (do_norm) {
    float s = x * x;
#pragma unroll
    for (int off = 32; off; off >>= 1) s += __shfl_xor(s, off, 64);
    inv = 1.0f / fmaxf(sqrtf(s), 1e-12f);
  }
  out[((size_t)(b * 8 + h) * Nn + n) * 64 + l] = x * inv;
}

// ---------- sim = q·k per head; store E = exp((sim-1)/eps)  [128][256][576] ----------
__global__ __launch_bounds__(256) void simE_k(const float* __restrict__ qn,
                                              const float* __restrict__ kn,
                                              float* __restrict__ E) {
  const int s = blockIdx.x, i0 = blockIdx.y << 6, j0 = blockIdx.z << 6;
  __shared__ alignas(16) float Qs[16][68];
  __shared__ alignas(16) float Ks[16][68];
  const int tid = threadIdx.x;
  const int tx = tid & 15, ty = tid >> 4;
  const int lm = tid >> 2, lk = (tid & 3) << 2;
  const float* Qp = qn + ((size_t)s * 256 + i0 + lm) * 64 + lk;
  const float* Kp = kn + ((size_t)s * 576 + j0 + lm) * 64 + lk;
  float acc[4][4] = {};
  for (int c0 = 0; c0 < 64; c0 += 16) {
    float4 qv = *(const float4*)(Qp + c0);
    float4 kv = *(const float4*)(Kp + c0);
    __syncthreads();
    Qs[lk + 0][lm] = qv.x; Qs[lk + 1][lm] = qv.y; Qs[lk + 2][lm] = qv.z; Qs[lk + 3][lm] = qv.w;
    Ks[lk + 0][lm] = kv.x; Ks[lk + 1][lm] = kv.y; Ks[lk + 2][lm] = kv.z; Ks[lk + 3][lm] = kv.w;
    __syncthreads();
#pragma unroll
    for (int kk = 0; kk < 16; ++kk) {
      float4 av = *(const float4*)&Qs[kk][ty << 2];
      float4 bv = *(const float4*)&Ks[kk][tx << 2];
      float ar[4] = {av.x, av.y, av.z, av.w};
      float br[4] = {bv.x, bv.y, bv.z, bv.w};
#pragma unroll
      for (int a = 0; a < 4; ++a)
#pragma unroll
        for (int b = 0; b < 4; ++b) acc[a][b] = fmaf(ar[a], br[b], acc[a][b]);
    }
  }
  float* Ep = E + (size_t)s * 147456;
#pragma unroll
  for (int a = 0; a < 4; ++a) {
    float4 o;
    o.x = __expf((acc[a][0] - 1.0f) * INV_EPS);
    o.y = __expf((acc[a][1] - 1.0f) * INV_EPS);
    o.z = __expf((acc[a][2] - 1.0f) * INV_EPS);
    o.w = __expf((acc[a][3] - 1.0f) * INV_EPS);
    *(float4*)&Ep[(size_t)(i0 + (ty << 2) + a) * 576 + j0 + (tx << 2)] = o;
  }
}

// ---------------- Sinkhorn v4: register-resident E as MFMA fragments ----------------
// 2 wgs per (b,h) slice; each wg holds its 128x576 E-half as bf16 MFMA fragments in
// VGPRs (72 VGPR/thread, staged once through LDS). Per iteration both matvecs
// (r = E.bv, c = E^T.au) run on the matrix pipe; au/bv carried as hi+lo bf16 pairs
// so vector rounding ~2^-16 (numerics == E-bf16-only, as R3). Cross-wg exchange:
// relaxed agent atomics + counter spin (fence-free, as R3).
__device__ __forceinline__ unsigned int f2bf(float f) {  // RNE f32->bf16
  unsigned int u = __float_as_uint(f);
  return (u + 0x7FFFu + ((u >> 16) & 1u)) >> 16;
}

#define SK_SMEM 147456

__global__ __launch_bounds__(1024, 1) void sinkhorn4_k(const float* __restrict__ E,
                                                       float* __restrict__ gA,
                                                       float* __restrict__ gB,
                                                       float* __restrict__ gpart,
                                                       unsigned int* __restrict__ cnt,
                                                       float C_mu, float C_nu) {
  extern __shared__ char smem[];
  const int g = blockIdx.x;
  const int s = g >> 1, rh = g & 1, pg = g ^ 1;
  const int tid = threadIdx.x, w = tid >> 6, l = tid & 63;
  const int li = l & 15, lg = l >> 4;
  float* myPart = gpart + (size_t)g * 1280;
  float* prPart = gpart + (size_t)pg * 1280;
  unsigned int* cntp = cnt + (size_t)s * 32;

  // ---- stage E half into LDS as bf16 (one-time) ----
  unsigned short* Est = (unsigned short*)smem;  // [128][576]
  {
    const float4* Eg4 = (const float4*)(E + (size_t)s * 147456 + (size_t)rh * 73728);
    for (int idx = tid; idx < 18432; idx += 1024) {
      float4 f = Eg4[idx];
      uint2 pk;
      pk.x = f2bf(f.x) | (f2bf(f.y) << 16);
      pk.y = f2bf(f.z) | (f2bf(f.w) << 16);
      ((uint2*)Est)[idx] = pk;
    }
  }
  __syncthreads();

  // ---- extract fragments into registers ----
  // matvec1 (r = E.bv): wave w: row-tile rt = w&7 (rows rt*16..+15), k-half kh = w>>3.
  // A-frag tile kt9: A[m=li][k=8*lg+j] = E[rt*16+li][(kh*9+kt9)*32 + 8*lg + j]
  const int rt = w & 7, kh = w >> 3;
  short8 afr[9];
#pragma unroll
  for (int k9 = 0; k9 < 9; ++k9) {
    const int ktg = kh * 9 + k9;
    afr[k9] = *(const short8*)(Est + (rt * 16 + li) * 576 + ktg * 32 + 8 * lg);
  }
  // matvec2 (c = E^T.au): kt-major: wave w: kt = w>>2 (rows kt*32..+31), n-tiles
  // ntbase..ntbase+8.  B-frag: B[k=8*lg+j][n=li] = E[kt*32+8*lg+j][nt*16+li]
  const int ktB = w >> 2, ntbase = (w & 3) * 9;
  short8 bfr[9];
#pragma unroll
  for (int p9 = 0; p9 < 9; ++p9) {
    const unsigned short* p = Est + (ktB * 32 + 8 * lg) * 576 + (ntbase + p9) * 16 + li;
    Pk pk;
    pk.u.x = (unsigned int)p[0]    | ((unsigned int)p[576]  << 16);
    pk.u.y = (unsigned int)p[1152] | ((unsigned int)p[1728] << 16);
    pk.u.z = (unsigned int)p[2304] | ((unsigned int)p[2880] << 16);
    pk.u.w = (unsigned int)p[3456] | ((unsigned int)p[4032] << 16);
    bfr[p9] = pk.s;
  }
  __syncthreads();

  // ---- overlay loop arrays onto smem (staging data fully consumed) ----
  float* uu = (float*)smem;                 // 128
  float* vv = uu + 128;                     // 576
  unsigned int* au_h = (unsigned int*)(vv + 576);  // 64  (128 bf16 pairs)
  unsigned int* au_l = au_h + 64;           // 64
  unsigned int* bv_h = au_l + 64;           // 288 (576 bf16 pairs)
  unsigned int* bv_l = bv_h + 288;          // 288
  float* rpart = (float*)(bv_l + 288);      // [2][128]
  float* colpart = rpart + 256;             // 576
  float* red = colpart + 576;               // 32

  if (tid < 128) uu[tid] = 0.0f;
  if (tid < 576) vv[tid] = 0.0f;
  if (tid < 32) red[tid] = 0.0f;
  __syncthreads();

  for (int t = 0; t < 100; ++t) {
    const float Su = red[0], Sv = red[1];
    // ---- Phase A: exponentiate + hi/lo bf16 pack ----
    if (tid < 64) {
      float2 up = *(const float2*)&uu[2 * tid];
      float a0 = __expf((up.x - Su) * INV_EPS);
      float a1 = __expf((up.y - Su) * INV_EPS);
      unsigned int h0 = f2bf(a0), h1 = f2bf(a1);
      float r0 = a0 - __uint_as_float(h0 << 16);
      float r1 = a1 - __uint_as_float(h1 << 16);
      au_h[tid] = h0 | (h1 << 16);
      au_l[tid] = f2bf(r0) | (f2bf(r1) << 16);
    } else if (tid < 352) {
      const int j = tid - 64;
      float2 vp = *(const float2*)&vv[2 * j];
      float b0 = __expf((vp.x - Sv) * INV_EPS);
      float b1 = __expf((vp.y - Sv) * INV_EPS);
      unsigned int h0 = f2bf(b0), h1 = f2bf(b1);
      float r0 = b0 - __uint_as_float(h0 << 16);
      float r1 = b1 - __uint_as_float(h1 << 16);
      bv_h[j] = h0 | (h1 << 16);
      bv_l[j] = f2bf(r0) | (f2bf(r1) << 16);
    } else if (tid < 928) {
      colpart[tid - 352] = 0.0f;
    }
    __syncthreads();

    // ---- Phase B: MFMA matvecs ----
    // matvec1: row sums (k-split across wave pairs)
    {
      f32x4 accA = {0.f, 0.f, 0.f, 0.f}, accB = {0.f, 0.f, 0.f, 0.f};
#pragma unroll
      for (int k9 = 0; k9 < 9; ++k9) {
        const int ktg = kh * 9 + k9;
        Pk bh, bl;
        bh.u = *(const uint4*)&bv_h[ktg * 16 + 4 * lg];
        bl.u = *(const uint4*)&bv_l[ktg * 16 + 4 * lg];
        accA = __builtin_amdgcn_mfma_f32_16x16x32_bf16(afr[k9], bh.s, accA, 0, 0, 0);
        accB = __builtin_amdgcn_mfma_f32_16x16x32_bf16(afr[k9], bl.s, accB, 0, 0, 0);
      }
      f32x4 r = accA + accB;
      if (li == 0) *(f32x4*)&rpart[kh * 128 + rt * 16 + 4 * lg] = r;
    }
    // matvec2: col partial sums (each wave owns k-tile ktB, n-tiles ntbase..+8)
    {
      Pk ah, al;
      ah.u = *(const uint4*)&au_h[ktB * 16 + 4 * lg];
      al.u = *(const uint4*)&au_l[ktB * 16 + 4 * lg];
#pragma unroll
      for (int p9 = 0; p9 < 9; ++p9) {
        f32x4 acc2 = {0.f, 0.f, 0.f, 0.f};
        acc2 = __builtin_amdgcn_mfma_f32_16x16x32_bf16(ah.s, bfr[p9], acc2, 0, 0, 0);
        acc2 = __builtin_amdgcn_mfma_f32_16x16x32_bf16(al.s, bfr[p9], acc2, 0, 0, 0);
        if (l < 16) atomicAdd(&colpart[(ntbase + p9) * 16 + l], acc2[0]);
      }
    }
    __syncthreads();

    // ---- Phase C1: u-update + publish (relaxed agent atomics) ----
    const int par = t & 1;
    float csMine = 0.0f;
    if (tid < 576) {
      csMine = colpart[tid];
      __hip_atomic_store(&myPart[par * 640 + tid], csMine, __ATOMIC_RELAXED,
                         __HIP_MEMORY_SCOPE_AGENT);
    } else if (tid < 704) {
      const int i = tid - 576;
      float rs = rpart[i] + rpart[128 + i];
      float un = C_mu - Sv - EPS_OT * __logf(rs);
      uu[i] = un;
      float um = un;
#pragma unroll
      for (int off = 32; off; off >>= 1) um = fmaxf(um, __shfl_xor(um, off, 64));
      if (l == 0) {
        __hip_atomic_store(&myPart[par * 640 + 576 + (w - 9)], um, __ATOMIC_RELAXED,
                           __HIP_MEMORY_SCOPE_AGENT);
        red[24 + (w - 9)] = um;
      }
    }
    __builtin_amdgcn_s_waitcnt(0);  // drain this wave's stores (ACK at MALL)
    __syncthreads();                // all waves drained + arrived
    if (tid == 0) {
      __hip_atomic_fetch_add(cntp, 1u, __ATOMIC_RELAXED, __HIP_MEMORY_SCOPE_AGENT);
      const unsigned int target = 2u * (unsigned int)(t + 1);
      while (__hip_atomic_load(cntp, __ATOMIC_RELAXED, __HIP_MEMORY_SCOPE_AGENT) < target) {
        __builtin_amdgcn_s_sleep(2);
      }
    }
    __syncthreads();

    // ---- Phase C2: v-update (both wgs identical) + next-iteration shifts ----
    float vmx = -3.0e38f;
    if (tid < 576) {
      float prc = __hip_atomic_load(&prPart[par * 640 + tid], __ATOMIC_RELAXED,
                                    __HIP_MEMORY_SCOPE_AGENT);
      float vn = C_nu - Su - EPS_OT * __logf(csMine + prc);
      vv[tid] = vn;
      vmx = vn;
    }
#pragma unroll
    for (int off = 32; off; off >>= 1) vmx = fmaxf(vmx, __shfl_xor(vmx, off, 64));
    if (l == 0 && w < 9) red[8 + w] = vmx;
    __syncthreads();
    if (tid == 0) {
      float sv = red[8];
#pragma unroll
      for (int q = 1; q < 9; ++q) sv = fmaxf(sv, red[8 + q]);
      red[1] = sv;
      float p0 = __hip_atomic_load(&prPart[par * 640 + 576], __ATOMIC_RELAXED,
                                   __HIP_MEMORY_SCOPE_AGENT);
      float p1 = __hip_atomic_load(&prPart[par * 640 + 577], __ATOMIC_RELAXED,
                                   __HIP_MEMORY_SCOPE_AGENT);
      red[0] = fmaxf(fmaxf(red[24], red[25]), fmaxf(p0, p1));
    }
    __syncthreads();
  }
  if (tid < 128) gA[(size_t)s * 256 + rh * 128 + tid] = uu[tid] * INV_EPS;
  if (rh == 0 && tid < 576) gB[(size_t)s * 576 + tid] = vv[tid] * INV_EPS + 11.9012851f;  // +ln(147456)
}

// --------------- out[b,i,h*64+c] = sum_j score(i,j) * V[j,c], per slice ---------------
__global__ __launch_bounds__(256) void scorev_k(const float* __restrict__ E,
                                                const float* __restrict__ V,
                                                const float* __restrict__ gA,
                                                const float* __restrict__ gB,
                                                float* __restrict__ Y) {
  const int s = blockIdx.x, i0 = blockIdx.y << 6;
  __shared__ alignas(16) float Ps[16][68];
  __shared__ alignas(16) float Vs[16][68];
  __shared__ float gBl[576];
  __shared__ float gAs[64];
  const int tid = threadIdx.x;
  const int tx = tid & 15, ty = tid >> 4;
  const int lm = tid >> 2, lk = (tid & 3) << 2;
  for (int t = tid; t < 576; t += 256) gBl[t] = gB[(size_t)s * 576 + t];
  if (tid < 64) gAs[tid] = gA[(size_t)s * 256 + i0 + tid];
  const float* Ep = E + (size_t)s * 147456 + (size_t)(i0 + lm) * 576;
  const float* Vp = V + (size_t)s * 576 * 64;
  float acc[4][4] = {};
  __syncthreads();
  for (int j0 = 0; j0 < 576; j0 += 16) {
    float4 e4 = *(const float4*)(Ep + j0 + lk);
    float4 v4 = *(const float4*)(Vp + (size_t)(j0 + ty) * 64 + (tx << 2));
    const float ga = gAs[lm];
    __syncthreads();
    {
      float le, p;
      le = __logf(e4.x); p = __expf(le + ga + gBl[j0 + lk + 0]); Ps[lk + 0][lm] = (1.0f + EPS_OT * le) * p;
      le = __logf(e4.y); p = __expf(le + ga + gBl[j0 + lk + 1]); Ps[lk + 1][lm] = (1.0f + EPS_OT * le) * p;
      le = __logf(e4.z); p = __expf(le + ga + gBl[j0 + lk + 2]); Ps[lk + 2][lm] = (1.0f + EPS_OT * le) * p;
      le = __logf(e4.w); p = __expf(le + ga + gBl[j0 + lk + 3]); Ps[lk + 3][lm] = (1.0f + EPS_OT * le) * p;
    }
    *(float4*)&Vs[ty][tx << 2] = v4;
    __syncthreads();
#pragma unroll
    for (int kk = 0; kk < 16; ++kk) {
      float4 av = *(const float4*)&Ps[kk][ty << 2];
      float4 bvv = *(const float4*)&Vs[kk][tx << 2];
      float ar[4] = {av.x, av.y, av.z, av.w};
      float br[4] = {bvv.x, bvv.y, bvv.z, bvv.w};
#pragma unroll
      for (int a = 0; a < 4; ++a)
#pragma unroll
        for (int b = 0; b < 4; ++b) acc[a][b] = fmaf(ar[a], br[b], acc[a][b]);
    }
  }
  const int b = s >> 3, h = s & 7;
#pragma unroll
  for (int a = 0; a < 4; ++a) {
    float4 o = {acc[a][0], acc[a][1], acc[a][2], acc[a][3]};
    *(float4*)&Y[((size_t)(b * 256 + i0 + (ty << 2) + a) << 9) + (h << 6) + (tx << 2)] = o;
  }
}

// ------------------------- final row l2norm (plain division) -------------------------
__global__ __launch_bounds__(256) void rownorm_k(const float* __restrict__ X,
                                                 float* __restrict__ out) {
  const size_t row = blockIdx.x;
  const int tid = threadIdx.x;
  float x0 = X[(row << 9) + tid], x1 = X[(row << 9) + 256 + tid];
  float st = fmaf(x0, x0, x1 * x1);
#pragma unroll
  for (int off = 32; off; off >>= 1) st += __shfl_xor(st, off, 64);
  __shared__ float ps[4];
  if ((tid & 63) == 0) ps[tid >> 6] = st;
  __syncthreads();
  const float inv = 1.0f / sqrtf(ps[0] + ps[1] + ps[2] + ps[3]);
  out[(row << 9) + tid] = x0 * inv;
  out[(row << 9) + 256 + tid] = x1 * inv;
}

extern "C" void kernel_launch(void* const* d_in, const int* in_sizes, int n_in,
                              void* d_out, int out_size, void* d_ws, size_t ws_size,
                              hipStream_t stream) {
  const float* F_t = (const float*)d_in[0];
  const float* F_s = (const float*)d_in[1];
  const float* Wq = (const float*)d_in[2];
  const float* bq = (const float*)d_in[3];
  const float* Wk = (const float*)d_in[4];
  const float* bk = (const float*)d_in[5];
  const float* Wv = (const float*)d_in[6];
  const float* bvb = (const float*)d_in[7];
  const float* Wp = (const float*)d_in[8];
  const float* bp = (const float*)d_in[9];
  float* out = (float*)d_out;
  float* ws = (float*)d_ws;

  float* T0 = ws;                  // 4,718,592 floats
  float* T1 = T0 + 4718592;        // 2,097,152 (dead during sinkhorn -> hosts cnt+gpart)
  float* qn = T1 + 2097152;        // 2,097,152  [B,H,256,64]
  float* kn = qn + 2097152;        // 4,718,592  [B,H,576,64]
  float* vn = kn + 4718592;        // 4,718,592  [B,H,576,64]
  float* E  = vn + 4718592;        // 18,874,368 [128,256,576]
  float* gA = E + 18874368;        // 32,768
  float* gB = gA + 32768;          // 73,728

  unsigned int* cnt = (unsigned int*)T1;  // 128 slices * 32-int stride = 16 KB
  float* gpart = T1 + 4096;               // 256 wgs * 2 * 640 floats = 1.31 MB

  const float C_mu = (float)(0.05 * log(1.0 / 256.0 + 1e-8));
  const float C_nu = (float)(0.05 * log(1.0 / 576.0 + 1e-8));

  hipMemsetAsync(cnt, 0, 128 * 32 * sizeof(unsigned int), stream);
  (void)hipFuncSetAttribute((const void*)sinkhorn4_k,
                            hipFuncAttributeMaxDynamicSharedMemorySize, SK_SMEM);

  gemm_xwT<<<dim3(64, 8), 256, 0, stream>>>(F_t, Wq, bq, T0, 4096);
  headnorm_k<<<8192, 256, 0, stream>>>(T0, qn, 256, 1);
  gemm_xwT<<<dim3(144, 8), 256, 0, stream>>>(F_s, Wk, bk, T0, 9216);
  headnorm_k<<<18432, 256, 0, stream>>>(T0, kn, 576, 1);
  gemm_xwT<<<dim3(144, 8), 256, 0, stream>>>(F_s, Wv, bvb, T0, 9216);
  headnorm_k<<<18432, 256, 0, stream>>>(T0, vn, 576, 0);
  simE_k<<<dim3(128, 4, 9), 256, 0, stream>>>(qn, kn, E);
  sinkhorn4_k<<<256, 1024, SK_SMEM, stream>>>(E, gA, gB, gpart, cnt, C_mu, C_nu);
  scorev_k<<<dim3(128, 4), 256, 0, stream>>>(E, vn, gA, gB, T0);
  gemm_xwT<<<dim3(64, 8), 256, 0, stream>>>(T0, Wp, bp, T1, 4096);
  rownorm_k<<<4096, 256, 0, stream>>>(T1, out);
}

// Round 5
// 560.050 us; speedup vs baseline: 8.1561x; 1.8928x over previous
//
#include <hip/hip_runtime.h>
#include <math.h>

#define EPS_OT 0.05f
#define INV_EPS 20.0f

typedef unsigned short ushort_t;
typedef __attribute__((ext_vector_type(8))) short short8;
typedef __attribute__((ext_vector_type(4))) float f32x4;
union Pk { uint4 u; short8 s; };

__device__ __forceinline__ unsigned int f2bf(float f) {  // RNE f32->bf16
  unsigned int u = __float_as_uint(f);
  return (u + 0x7FFFu + ((u >> 16) & 1u)) >> 16;
}
__device__ __forceinline__ float bf2f(unsigned int u) { return __uint_as_float(u << 16); }

// pack float4 -> hi uint2 + lo uint2 (bf16 pairs)
__device__ __forceinline__ void hl4(const float4 f, uint2& h, uint2& l) {
  unsigned int h0 = f2bf(f.x), h1 = f2bf(f.y), h2 = f2bf(f.z), h3 = f2bf(f.w);
  h.x = h0 | (h1 << 16); h.y = h2 | (h3 << 16);
  l.x = f2bf(f.x - bf2f(h0)) | (f2bf(f.y - bf2f(h1)) << 16);
  l.y = f2bf(f.z - bf2f(h2)) | (f2bf(f.w - bf2f(h3)) << 16);
}

// ---------- MFMA GEMM: Y[M,512] = X[M,512] @ W[512,512]^T + bias (hi/lo bf16) ----------
__global__ __launch_bounds__(256) void gemm_bf16_k(const float* __restrict__ X,
                                                   const float* __restrict__ W,
                                                   const float* __restrict__ bias,
                                                   float* __restrict__ Y, int M) {
  __shared__ ushort_t Xh[64][72], Xl[64][72], Wh[64][72], Wl[64][72];
  const int tid = threadIdx.x;
  const int w = tid >> 6, l = tid & 63, li = l & 15, lg = l >> 4;
  const int r = tid >> 2, cg = tid & 3;
  const int m0 = blockIdx.x << 6, n0 = blockIdx.y << 6;
  const float* Xp = X + (size_t)(m0 + r) * 512 + cg * 16;
  const float* Wp = W + (size_t)(n0 + r) * 512 + cg * 16;
  f32x4 acc[4] = {};
  for (int k0 = 0; k0 < 512; k0 += 64) {
    float4 x0 = *(const float4*)(Xp + k0), x1 = *(const float4*)(Xp + k0 + 4);
    float4 x2 = *(const float4*)(Xp + k0 + 8), x3 = *(const float4*)(Xp + k0 + 12);
    float4 w0 = *(const float4*)(Wp + k0), w1 = *(const float4*)(Wp + k0 + 4);
    float4 w2 = *(const float4*)(Wp + k0 + 8), w3 = *(const float4*)(Wp + k0 + 12);
    __syncthreads();
    uint4 ph, pl;
    hl4(x0, *(uint2*)&ph.x, *(uint2*)&pl.x); hl4(x1, *(uint2*)&ph.z, *(uint2*)&pl.z);
    *(uint4*)&Xh[r][cg * 16] = ph; *(uint4*)&Xl[r][cg * 16] = pl;
    hl4(x2, *(uint2*)&ph.x, *(uint2*)&pl.x); hl4(x3, *(uint2*)&ph.z, *(uint2*)&pl.z);
    *(uint4*)&Xh[r][cg * 16 + 8] = ph; *(uint4*)&Xl[r][cg * 16 + 8] = pl;
    hl4(w0, *(uint2*)&ph.x, *(uint2*)&pl.x); hl4(w1, *(uint2*)&ph.z, *(uint2*)&pl.z);
    *(uint4*)&Wh[r][cg * 16] = ph; *(uint4*)&Wl[r][cg * 16] = pl;
    hl4(w2, *(uint2*)&ph.x, *(uint2*)&pl.x); hl4(w3, *(uint2*)&ph.z, *(uint2*)&pl.z);
    *(uint4*)&Wh[r][cg * 16 + 8] = ph; *(uint4*)&Wl[r][cg * 16 + 8] = pl;
    __syncthreads();
#pragma unroll
    for (int kst = 0; kst < 2; ++kst) {
      short8 ah = *(const short8*)&Xh[16 * w + li][kst * 32 + 8 * lg];
      short8 al = *(const short8*)&Xl[16 * w + li][kst * 32 + 8 * lg];
#pragma unroll
      for (int nt = 0; nt < 4; ++nt) {
        short8 bh = *(const short8*)&Wh[nt * 16 + li][kst * 32 + 8 * lg];
        short8 bl = *(const short8*)&Wl[nt * 16 + li][kst * 32 + 8 * lg];
        acc[nt] = __builtin_amdgcn_mfma_f32_16x16x32_bf16(ah, bh, acc[nt], 0, 0, 0);
        acc[nt] = __builtin_amdgcn_mfma_f32_16x16x32_bf16(ah, bl, acc[nt], 0, 0, 0);
        acc[nt] = __builtin_amdgcn_mfma_f32_16x16x32_bf16(al, bh, acc[nt], 0, 0, 0);
      }
    }
  }
#pragma unroll
  for (int nt = 0; nt < 4; ++nt) {
    float bb = bias[n0 + nt * 16 + li];
#pragma unroll
    for (int reg = 0; reg < 4; ++reg)
      Y[(size_t)(m0 + 16 * w + 4 * lg + reg) * 512 + n0 + nt * 16 + li] = acc[nt][reg] + bb;
  }
}

// ------- per-head l2norm + relayout -> hi/lo bf16 [B*H][Nn][64] (for q and k) -------
__global__ __launch_bounds__(256) void headnorm2_k(const float* __restrict__ in,
                                                   ushort_t* __restrict__ oh,
                                                   ushort_t* __restrict__ ol, int Nn) {
  const int wv = threadIdx.x >> 6, l = threadIdx.x & 63;
  const int chunk = (blockIdx.x << 2) + wv;
  const int h = chunk & 7;
  const int bn = chunk >> 3;
  const int n = bn % Nn, b = bn / Nn;
  float x = in[((size_t)bn << 9) + (h << 6) + l];
  float s = x * x;
#pragma unroll
  for (int off = 32; off; off >>= 1) s += __shfl_xor(s, off, 64);
  float y = x / fmaxf(sqrtf(s), 1e-12f);
  unsigned int hi = f2bf(y);
  const size_t idx = ((size_t)(b * 8 + h) * Nn + n) * 64 + l;
  oh[idx] = (ushort_t)hi;
  ol[idx] = (ushort_t)f2bf(y - bf2f(hi));
}

// ---- V: relayout+transpose T0 [B,N2,H*64] fp32 -> vt [128][64][576] bf16 ----
__global__ __launch_bounds__(256) void transpose_v_k(const float* __restrict__ X,
                                                     ushort_t* __restrict__ vt) {
  __shared__ ushort_t Vs[64][72];
  const int s = blockIdx.x, j0 = blockIdx.y << 6;
  const int b = s >> 3, h = s & 7;
  const int tid = threadIdx.x;
  const int r = tid >> 2, cg = tid & 3;
  const float* p = X + ((size_t)(b * 576 + j0 + r) << 9) + (h << 6) + cg * 16;
  float4 a0 = *(const float4*)p, a1 = *(const float4*)(p + 4);
  float4 a2 = *(const float4*)(p + 8), a3 = *(const float4*)(p + 12);
  uint4 ph;
  ph.x = f2bf(a0.x) | (f2bf(a0.y) << 16); ph.y = f2bf(a0.z) | (f2bf(a0.w) << 16);
  ph.z = f2bf(a1.x) | (f2bf(a1.y) << 16); ph.w = f2bf(a1.z) | (f2bf(a1.w) << 16);
  *(uint4*)&Vs[r][cg * 16] = ph;
  ph.x = f2bf(a2.x) | (f2bf(a2.y) << 16); ph.y = f2bf(a2.z) | (f2bf(a2.w) << 16);
  ph.z = f2bf(a3.x) | (f2bf(a3.y) << 16); ph.w = f2bf(a3.z) | (f2bf(a3.w) << 16);
  *(uint4*)&Vs[r][cg * 16 + 8] = ph;
  __syncthreads();
  const int c = tid >> 2, jc = tid & 3;
  ushort_t tmp[16];
#pragma unroll
  for (int jj = 0; jj < 16; ++jj) tmp[jj] = Vs[jc * 16 + jj][c];
  ushort_t* op = vt + ((size_t)s * 64 + c) * 576 + j0 + jc * 16;
  *(uint4*)op = *(uint4*)&tmp[0];
  *(uint4*)(op + 8) = *(uint4*)&tmp[8];
}

// ---------- simE: E[s][i][j] = bf16(exp((q.k - 1)*20)), MFMA hi/lo ----------
__global__ __launch_bounds__(256) void simE2_k(const ushort_t* __restrict__ qh,
                                               const ushort_t* __restrict__ ql,
                                               const ushort_t* __restrict__ kh,
                                               const ushort_t* __restrict__ kl,
                                               ushort_t* __restrict__ E) {
  const int s = blockIdx.x, i0 = blockIdx.y << 6, j0 = blockIdx.z << 6;
  const int tid = threadIdx.x;
  const int w = tid >> 6, l = tid & 63, li = l & 15, lg = l >> 4;
  const size_t qoff = ((size_t)s * 256 + i0 + 16 * w + li) * 64 + 8 * lg;
  short8 aH0 = *(const short8*)(qh + qoff), aH1 = *(const short8*)(qh + qoff + 32);
  short8 aL0 = *(const short8*)(ql + qoff), aL1 = *(const short8*)(ql + qoff + 32);
  f32x4 acc[4] = {};
#pragma unroll
  for (int nt = 0; nt < 4; ++nt) {
    const size_t koff = ((size_t)s * 576 + j0 + nt * 16 + li) * 64 + 8 * lg;
    short8 bH0 = *(const short8*)(kh + koff), bH1 = *(const short8*)(kh + koff + 32);
    short8 bL0 = *(const short8*)(kl + koff), bL1 = *(const short8*)(kl + koff + 32);
    acc[nt] = __builtin_amdgcn_mfma_f32_16x16x32_bf16(aH0, bH0, acc[nt], 0, 0, 0);
    acc[nt] = __builtin_amdgcn_mfma_f32_16x16x32_bf16(aH1, bH1, acc[nt], 0, 0, 0);
    acc[nt] = __builtin_amdgcn_mfma_f32_16x16x32_bf16(aH0, bL0, acc[nt], 0, 0, 0);
    acc[nt] = __builtin_amdgcn_mfma_f32_16x16x32_bf16(aH1, bL1, acc[nt], 0, 0, 0);
    acc[nt] = __builtin_amdgcn_mfma_f32_16x16x32_bf16(aL0, bH0, acc[nt], 0, 0, 0);
    acc[nt] = __builtin_amdgcn_mfma_f32_16x16x32_bf16(aL1, bH1, acc[nt], 0, 0, 0);
  }
  ushort_t* Ep = E + (size_t)s * 147456;
#pragma unroll
  for (int nt = 0; nt < 4; ++nt)
#pragma unroll
    for (int reg = 0; reg < 4; ++reg) {
      float e = __expf((acc[nt][reg] - 1.0f) * INV_EPS);
      Ep[(size_t)(i0 + 16 * w + 4 * lg + reg) * 576 + j0 + nt * 16 + li] = (ushort_t)f2bf(e);
    }
}

// ---------------- Sinkhorn v5: register-resident E, shift-free, tag-based sync ----------------
// 2 wgs per slice; E half (128x576 bf16) in VGPR MFMA fragments. No max-shifts (exact
// algebra; exponents bounded for this data; clamp +-80 insurance). Cross-wg exchange:
// (value,tag) packed in one relaxed 8B agent atomic; per-thread poll. 3 barriers/iter.
#define SK_SMEM 147456

__global__ __launch_bounds__(1024, 1) void sinkhorn5_k(const ushort_t* __restrict__ E,
                                                       float* __restrict__ gA,
                                                       float* __restrict__ gB,
                                                       unsigned long long* __restrict__ gpart,
                                                       float C_mu, float C_nu) {
  extern __shared__ char smem[];
  const int g = blockIdx.x, s = g >> 1, rh = g & 1, pg = g ^ 1;
  const int tid = threadIdx.x, w = tid >> 6, l = tid & 63, li = l & 15, lg = l >> 4;
  unsigned long long* myP = gpart + (size_t)g * 1152;
  const unsigned long long* prP = gpart + (size_t)pg * 1152;

  // ---- stage E half (already bf16) into LDS ----
  ushort_t* Elds = (ushort_t*)smem;  // [128][576]
  {
    const uint4* Eg = (const uint4*)(E + (size_t)s * 147456 + (size_t)rh * 73728);
    uint4* El4 = (uint4*)Elds;
    for (int idx = tid; idx < 9216; idx += 1024) El4[idx] = Eg[idx];
  }
  __syncthreads();

  // ---- extract fragments (layouts proven in R4) ----
  const int rt = w & 7, khf = w >> 3;
  short8 afr[9];
#pragma unroll
  for (int k9 = 0; k9 < 9; ++k9)
    afr[k9] = *(const short8*)(Elds + (rt * 16 + li) * 576 + (khf * 9 + k9) * 32 + 8 * lg);
  const int ktB = w >> 2, ntb = (w & 3) * 9;
  short8 bfr[9];
#pragma unroll
  for (int p9 = 0; p9 < 9; ++p9) {
    const ushort_t* p = Elds + (ktB * 32 + 8 * lg) * 576 + (ntb + p9) * 16 + li;
    Pk pk;
    pk.u.x = (unsigned int)p[0]    | ((unsigned int)p[576]  << 16);
    pk.u.y = (unsigned int)p[1152] | ((unsigned int)p[1728] << 16);
    pk.u.z = (unsigned int)p[2304] | ((unsigned int)p[2880] << 16);
    pk.u.w = (unsigned int)p[3456] | ((unsigned int)p[4032] << 16);
    bfr[p9] = pk.s;
  }
  __syncthreads();

  // ---- overlay scratch ----
  float* uu = (float*)smem;                        // 128
  float* vv = uu + 128;                            // 576
  unsigned int* au_h = (unsigned int*)(vv + 576);  // 64
  unsigned int* au_l = au_h + 64;                  // 64
  unsigned int* bv_h = au_l + 64;                  // 288
  unsigned int* bv_l = bv_h + 288;                 // 288
  float* rpart = (float*)(bv_l + 288);             // 256
  float* colp = rpart + 256;                       // 4*576
  float* cso = colp + 2304;                        // 576
  if (tid < 64) { au_h[tid] = 0x3F803F80u; au_l[tid] = 0u; }
  if (tid < 288) { bv_h[tid] = 0x3F803F80u; bv_l[tid] = 0u; }
  __syncthreads();

  for (int t = 0; t < 100; ++t) {
    // ---- B: MFMA matvecs ----
    {
      f32x4 aA = {0.f, 0.f, 0.f, 0.f}, aB = {0.f, 0.f, 0.f, 0.f};
#pragma unroll
      for (int k9 = 0; k9 < 9; ++k9) {
        const int ktg = khf * 9 + k9;
        Pk bh, bl;
        bh.u = *(const uint4*)&bv_h[ktg * 16 + 4 * lg];
        bl.u = *(const uint4*)&bv_l[ktg * 16 + 4 * lg];
        aA = __builtin_amdgcn_mfma_f32_16x16x32_bf16(afr[k9], bh.s, aA, 0, 0, 0);
        aB = __builtin_amdgcn_mfma_f32_16x16x32_bf16(afr[k9], bl.s, aB, 0, 0, 0);
      }
      f32x4 rr = aA + aB;
      if (li == 0) *(f32x4*)&rpart[khf * 128 + rt * 16 + 4 * lg] = rr;
    }
    {
      Pk ah, al;
      ah.u = *(const uint4*)&au_h[ktB * 16 + 4 * lg];
      al.u = *(const uint4*)&au_l[ktB * 16 + 4 * lg];
      float* cp = colp + (w >> 2) * 576;
#pragma unroll
      for (int p9 = 0; p9 < 9; ++p9) {
        f32x4 a2 = {0.f, 0.f, 0.f, 0.f};
        a2 = __builtin_amdgcn_mfma_f32_16x16x32_bf16(ah.s, bfr[p9], a2, 0, 0, 0);
        a2 = __builtin_amdgcn_mfma_f32_16x16x32_bf16(al.s, bfr[p9], a2, 0, 0, 0);
        if (l < 16) cp[(ntb + p9) * 16 + l] = a2[0];
      }
    }
    __syncthreads();
    // ---- C1: publish colsums, local u-update + au pack ----
    const int par = t & 1;
    if (tid < 576) {
      float cs = colp[tid] + colp[576 + tid] + colp[1152 + tid] + colp[1728 + tid];
      cso[tid] = cs;
      unsigned long long pv = (unsigned long long)__float_as_uint(cs) |
                              ((unsigned long long)(unsigned int)(t + 1) << 32);
      __hip_atomic_store(&myP[par * 576 + tid], pv, __ATOMIC_RELAXED, __HIP_MEMORY_SCOPE_AGENT);
    } else if (tid < 640) {
      const int i2 = (tid - 576) * 2;
      float rs0 = rpart[i2] + rpart[128 + i2];
      float rs1 = rpart[i2 + 1] + rpart[129 + i2];
      float un0 = C_mu - EPS_OT * __logf(rs0);
      float un1 = C_mu - EPS_OT * __logf(rs1);
      uu[i2] = un0; uu[i2 + 1] = un1;
      float a0 = __expf(fminf(fmaxf(un0 * INV_EPS, -80.f), 80.f));
      float a1 = __expf(fminf(fmaxf(un1 * INV_EPS, -80.f), 80.f));
      unsigned int h0 = f2bf(a0), h1 = f2bf(a1);
      au_h[tid - 576] = h0 | (h1 << 16);
      au_l[tid - 576] = f2bf(a0 - bf2f(h0)) | (f2bf(a1 - bf2f(h1)) << 16);
    }
    __syncthreads();
    // ---- C2: poll partner colsums, v-update + bv pack ----
    if (tid < 288) {
      const int j0 = tid * 2;
      const unsigned int tg = (unsigned int)(t + 1);
      unsigned long long p0, p1;
      bool d0 = false, d1 = false;
      float pc0 = 0.f, pc1 = 0.f;
      while (!(d0 && d1)) {
        if (!d0) {
          p0 = __hip_atomic_load(&prP[par * 576 + j0], __ATOMIC_RELAXED, __HIP_MEMORY_SCOPE_AGENT);
          if ((unsigned int)(p0 >> 32) == tg) { pc0 = __uint_as_float((unsigned int)p0); d0 = true; }
        }
        if (!d1) {
          p1 = __hip_atomic_load(&prP[par * 576 + j0 + 1], __ATOMIC_RELAXED, __HIP_MEMORY_SCOPE_AGENT);
          if ((unsigned int)(p1 >> 32) == tg) { pc1 = __uint_as_float((unsigned int)p1); d1 = true; }
        }
        if (!(d0 && d1)) __builtin_amdgcn_s_sleep(1);
      }
      float vn0 = C_nu - EPS_OT * __logf(cso[j0] + pc0);
      float vn1 = C_nu - EPS_OT * __logf(cso[j0 + 1] + pc1);
      vv[j0] = vn0; vv[j0 + 1] = vn1;
      float b0 = __expf(fminf(fmaxf(vn0 * INV_EPS, -80.f), 80.f));
      float b1 = __expf(fminf(fmaxf(vn1 * INV_EPS, -80.f), 80.f));
      unsigned int h0 = f2bf(b0), h1 = f2bf(b1);
      bv_h[tid] = h0 | (h1 << 16);
      bv_l[tid] = f2bf(b0 - bf2f(h0)) | (f2bf(b1 - bf2f(h1)) << 16);
    }
    __syncthreads();
  }
  if (tid < 128) gA[(size_t)s * 256 + rh * 128 + tid] = uu[tid] * INV_EPS;
  if (rh == 0 && tid < 576) gB[(size_t)s * 576 + tid] = vv[tid] * INV_EPS + 11.9012851f;  // +ln(147456)
}

// ---------- scorev: out = score @ V via MFMA (hi/lo P, bf16 V from vt) ----------
__global__ __launch_bounds__(256) void scorev2_k(const ushort_t* __restrict__ E,
                                                 const ushort_t* __restrict__ vt,
                                                 const float* __restrict__ gA,
                                                 const float* __restrict__ gB,
                                                 float* __restrict__ Y) {
  __shared__ float gBs[576];
  const int s = blockIdx.x, i0 = blockIdx.y << 6;
  const int tid = threadIdx.x;
  const int w = tid >> 6, l = tid & 63, li = l & 15, lg = l >> 4;
  for (int j = tid; j < 576; j += 256) gBs[j] = gB[(size_t)s * 576 + j];
  const float ga = gA[(size_t)s * 256 + i0 + 16 * w + li];
  const ushort_t* Erow = E + (size_t)s * 147456 + (size_t)(i0 + 16 * w + li) * 576;
  f32x4 acc[4] = {};
  __syncthreads();
  for (int kst = 0; kst < 18; ++kst) {
    const int jb = kst * 32 + 8 * lg;
    Pk eu; eu.u = *(const uint4*)(Erow + jb);
    float pv[8], pl8[8];
#pragma unroll
    for (int jj = 0; jj < 8; ++jj) {
      unsigned int us = (unsigned int)(unsigned short)eu.s[jj];
      float e = bf2f(us);
      float le = __logf(e);
      float p = (1.0f + EPS_OT * le) * __expf(le + ga + gBs[jb + jj]);
      pv[jj] = p;
    }
    Pk ph, pl;
#pragma unroll
    for (int jj = 0; jj < 8; ++jj) {
      unsigned int h = f2bf(pv[jj]);
      ((unsigned short*)&ph.s)[jj] = (unsigned short)h;
      pl8[jj] = pv[jj] - bf2f(h);
    }
#pragma unroll
    for (int jj = 0; jj < 8; ++jj)
      ((unsigned short*)&pl.s)[jj] = (unsigned short)f2bf(pl8[jj]);
#pragma unroll
    for (int nt = 0; nt < 4; ++nt) {
      Pk vf; vf.u = *(const uint4*)(vt + ((size_t)s * 64 + nt * 16 + li) * 576 + jb);
      acc[nt] = __builtin_amdgcn_mfma_f32_16x16x32_bf16(ph.s, vf.s, acc[nt], 0, 0, 0);
      acc[nt] = __builtin_amdgcn_mfma_f32_16x16x32_bf16(pl.s, vf.s, acc[nt], 0, 0, 0);
    }
  }
  const int b = s >> 3, h = s & 7;
#pragma unroll
  for (int nt = 0; nt < 4; ++nt)
#pragma unroll
    for (int reg = 0; reg < 4; ++reg)
      Y[((size_t)(b * 256 + i0 + 16 * w + 4 * lg + reg) << 9) + (h << 6) + nt * 16 + li] =
          acc[nt][reg];
}

// ------------------------- final row l2norm (plain division) -------------------------
__global__ __launch_bounds__(256) void rownorm_k(const float* __restrict__ X,
                                                 float* __restrict__ out) {
  const size_t row = blockIdx.x;
  const int tid = threadIdx.x;
  float x0 = X[(row << 9) + tid], x1 = X[(row << 9) + 256 + tid];
  float st = fmaf(x0, x0, x1 * x1);
#pragma unroll
  for (int off = 32; off; off >>= 1) st += __shfl_xor(st, off, 64);
  __shared__ float ps[4];
  if ((tid & 63) == 0) ps[tid >> 6] = st;
  __syncthreads();
  const float inv = 1.0f / sqrtf(ps[0] + ps[1] + ps[2] + ps[3]);
  out[(row << 9) + tid] = x0 * inv;
  out[(row << 9) + 256 + tid] = x1 * inv;
}

extern "C" void kernel_launch(void* const* d_in, const int* in_sizes, int n_in,
                              void* d_out, int out_size, void* d_ws, size_t ws_size,
                              hipStream_t stream) {
  const float* F_t = (const float*)d_in[0];
  const float* F_s = (const float*)d_in[1];
  const float* Wq = (const float*)d_in[2];
  const float* bq = (const float*)d_in[3];
  const float* Wk = (const float*)d_in[4];
  const float* bk = (const float*)d_in[5];
  const float* Wv = (const float*)d_in[6];
  const float* bvb = (const float*)d_in[7];
  const float* Wp = (const float*)d_in[8];
  const float* bp = (const float*)d_in[9];
  float* out = (float*)d_out;
  float* ws = (float*)d_ws;

  float* T0 = ws;                          // 4,718,592 f32
  float* T1 = T0 + 4718592;                // 2,097,152 f32
  ushort_t* qh = (ushort_t*)(T1 + 2097152);  // 2,097,152 us
  ushort_t* ql = qh + 2097152;             // 2,097,152
  ushort_t* kh = ql + 2097152;             // 4,718,592
  ushort_t* kl = kh + 4718592;             // 4,718,592
  ushort_t* vt = kl + 4718592;             // 4,718,592  [128][64][576]
  ushort_t* Eb = vt + 4718592;             // 18,874,368 [128][256][576]
  float* gA = (float*)(Eb + 18874368);     // 32,768
  float* gB = gA + 32768;                  // 73,728
  unsigned long long* gpart = (unsigned long long*)(gB + 73728);  // 256*1152*8 B

  const float C_mu = (float)(0.05 * log(1.0 / 256.0 + 1e-8));
  const float C_nu = (float)(0.05 * log(1.0 / 576.0 + 1e-8));

  (void)hipFuncSetAttribute((const void*)sinkhorn5_k,
                            hipFuncAttributeMaxDynamicSharedMemorySize, SK_SMEM);

  gemm_bf16_k<<<dim3(64, 8), 256, 0, stream>>>(F_t, Wq, bq, T0, 4096);
  headnorm2_k<<<8192, 256, 0, stream>>>(T0, qh, ql, 256);
  gemm_bf16_k<<<dim3(144, 8), 256, 0, stream>>>(F_s, Wk, bk, T0, 9216);
  headnorm2_k<<<18432, 256, 0, stream>>>(T0, kh, kl, 576);
  gemm_bf16_k<<<dim3(144, 8), 256, 0, stream>>>(F_s, Wv, bvb, T0, 9216);
  transpose_v_k<<<dim3(128, 9), 256, 0, stream>>>(T0, vt);
  simE2_k<<<dim3(128, 4, 9), 256, 0, stream>>>(qh, ql, kh, kl, Eb);
  sinkhorn5_k<<<256, 1024, SK_SMEM, stream>>>(Eb, gA, gB, gpart, C_mu, C_nu);
  scorev2_k<<<dim3(128, 4), 256, 0, stream>>>(Eb, vt, gA, gB, T0);
  gemm_bf16_k<<<dim3(64, 8), 256, 0, stream>>>(T0, Wp, bp, T1, 4096);
  rownorm_k<<<4096, 256, 0, stream>>>(T1, out);
}

// Round 6
// 467.816 us; speedup vs baseline: 9.7641x; 1.1972x over previous
//
#include <hip/hip_runtime.h>
#include <math.h>

#define EPS_OT 0.05f
#define INV_EPS 20.0f

typedef unsigned short ushort_t;
typedef __attribute__((ext_vector_type(8))) short short8;
typedef __attribute__((ext_vector_type(4))) float f32x4;
union Pk { uint4 u; short8 s; };

__device__ __forceinline__ unsigned int f2bf(float f) {  // RNE f32->bf16
  unsigned int u = __float_as_uint(f);
  return (u + 0x7FFFu + ((u >> 16) & 1u)) >> 16;
}
__device__ __forceinline__ float bf2f(unsigned int u) { return __uint_as_float(u << 16); }

__device__ __forceinline__ void hl4(const float4 f, uint2& h, uint2& l) {
  unsigned int h0 = f2bf(f.x), h1 = f2bf(f.y), h2 = f2bf(f.z), h3 = f2bf(f.w);
  h.x = h0 | (h1 << 16); h.y = h2 | (h3 << 16);
  l.x = f2bf(f.x - bf2f(h0)) | (f2bf(f.y - bf2f(h1)) << 16);
  l.y = f2bf(f.z - bf2f(h2)) | (f2bf(f.w - bf2f(h3)) << 16);
}

// ================= shared GEMM main loop (64x64 tile, K=512, hi/lo bf16) =================
#define GEMM_BODY(XPTR, WPTR)                                                              \
  f32x4 acc[4] = {};                                                                       \
  for (int k0 = 0; k0 < 512; k0 += 64) {                                                   \
    float4 x0 = *(const float4*)(XPTR + k0), x1 = *(const float4*)(XPTR + k0 + 4);         \
    float4 x2 = *(const float4*)(XPTR + k0 + 8), x3 = *(const float4*)(XPTR + k0 + 12);    \
    float4 w0 = *(const float4*)(WPTR + k0), w1 = *(const float4*)(WPTR + k0 + 4);         \
    float4 w2 = *(const float4*)(WPTR + k0 + 8), w3 = *(const float4*)(WPTR + k0 + 12);    \
    __syncthreads();                                                                       \
    uint4 ph, pl;                                                                          \
    hl4(x0, *(uint2*)&ph.x, *(uint2*)&pl.x); hl4(x1, *(uint2*)&ph.z, *(uint2*)&pl.z);      \
    *(uint4*)&Xh[r][cg * 16] = ph; *(uint4*)&Xl[r][cg * 16] = pl;                          \
    hl4(x2, *(uint2*)&ph.x, *(uint2*)&pl.x); hl4(x3, *(uint2*)&ph.z, *(uint2*)&pl.z);      \
    *(uint4*)&Xh[r][cg * 16 + 8] = ph; *(uint4*)&Xl[r][cg * 16 + 8] = pl;                  \
    hl4(w0, *(uint2*)&ph.x, *(uint2*)&pl.x); hl4(w1, *(uint2*)&ph.z, *(uint2*)&pl.z);      \
    *(uint4*)&Wh[r][cg * 16] = ph; *(uint4*)&Wl[r][cg * 16] = pl;                          \
    hl4(w2, *(uint2*)&ph.x, *(uint2*)&pl.x); hl4(w3, *(uint2*)&ph.z, *(uint2*)&pl.z);      \
    *(uint4*)&Wh[r][cg * 16 + 8] = ph; *(uint4*)&Wl[r][cg * 16 + 8] = pl;                  \
    __syncthreads();                                                                       \
    _Pragma("unroll") for (int kst = 0; kst < 2; ++kst) {                                  \
      short8 ah = *(const short8*)&Xh[16 * w + li][kst * 32 + 8 * lg];                     \
      short8 al = *(const short8*)&Xl[16 * w + li][kst * 32 + 8 * lg];                     \
      _Pragma("unroll") for (int nt = 0; nt < 4; ++nt) {                                   \
        short8 bh = *(const short8*)&Wh[nt * 16 + li][kst * 32 + 8 * lg];                  \
        short8 bl = *(const short8*)&Wl[nt * 16 + li][kst * 32 + 8 * lg];                  \
        acc[nt] = __builtin_amdgcn_mfma_f32_16x16x32_bf16(ah, bh, acc[nt], 0, 0, 0);       \
        acc[nt] = __builtin_amdgcn_mfma_f32_16x16x32_bf16(ah, bl, acc[nt], 0, 0, 0);       \
        acc[nt] = __builtin_amdgcn_mfma_f32_16x16x32_bf16(al, bh, acc[nt], 0, 0, 0);       \
      }                                                                                    \
    }                                                                                      \
  }

// ---------------- plain GEMM (fp32 out): used for Wp ----------------
__global__ __launch_bounds__(256) void gemm_bf16_k(const float* __restrict__ X,
                                                   const float* __restrict__ W,
                                                   const float* __restrict__ bias,
                                                   float* __restrict__ Y, int M) {
  __shared__ ushort_t Xh[64][72], Xl[64][72], Wh[64][72], Wl[64][72];
  const int tid = threadIdx.x;
  const int w = tid >> 6, l = tid & 63, li = l & 15, lg = l >> 4;
  const int r = tid >> 2, cg = tid & 3;
  const int m0 = blockIdx.x << 6, n0 = blockIdx.y << 6;
  const float* Xp = X + (size_t)(m0 + r) * 512 + cg * 16;
  const float* Wp = W + (size_t)(n0 + r) * 512 + cg * 16;
  GEMM_BODY(Xp, Wp)
#pragma unroll
  for (int nt = 0; nt < 4; ++nt) {
    float bb = bias[n0 + nt * 16 + li];
#pragma unroll
    for (int reg = 0; reg < 4; ++reg)
      Y[(size_t)(m0 + 16 * w + 4 * lg + reg) * 512 + n0 + nt * 16 + li] = acc[nt][reg] + bb;
  }
}

// ------- fused GEMM + per-head l2norm -> hi/lo bf16 [B*H][Nn][64] (q and k) -------
__global__ __launch_bounds__(256) void gemmnorm_k(const float* __restrict__ X,
                                                  const float* __restrict__ W,
                                                  const float* __restrict__ bias,
                                                  ushort_t* __restrict__ oh,
                                                  ushort_t* __restrict__ ol, int Nn) {
  __shared__ ushort_t Xh[64][72], Xl[64][72], Wh[64][72], Wl[64][72];
  const int tid = threadIdx.x;
  const int w = tid >> 6, l = tid & 63, li = l & 15, lg = l >> 4;
  const int r = tid >> 2, cg = tid & 3;
  const int m0 = blockIdx.x << 6;
  const int h = blockIdx.y, n0 = h << 6;
  const float* Xp = X + (size_t)(m0 + r) * 512 + cg * 16;
  const float* Wp = W + (size_t)(n0 + r) * 512 + cg * 16;
  GEMM_BODY(Xp, Wp)
  float v[4][4];
  float ss[4] = {0.f, 0.f, 0.f, 0.f};
#pragma unroll
  for (int nt = 0; nt < 4; ++nt) {
    float bb = bias[n0 + nt * 16 + li];
#pragma unroll
    for (int reg = 0; reg < 4; ++reg) {
      float y = acc[nt][reg] + bb;
      v[nt][reg] = y;
      ss[reg] = fmaf(y, y, ss[reg]);
    }
  }
#pragma unroll
  for (int off = 1; off < 16; off <<= 1)
#pragma unroll
    for (int reg = 0; reg < 4; ++reg) ss[reg] += __shfl_xor(ss[reg], off, 64);
  const int b = m0 / Nn;
  const int nbase = m0 - b * Nn;
  const size_t base = ((size_t)(b * 8 + h) * Nn + nbase + 16 * w + 4 * lg) * 64;
#pragma unroll
  for (int reg = 0; reg < 4; ++reg) {
    float inv = 1.0f / fmaxf(sqrtf(ss[reg]), 1e-12f);
#pragma unroll
    for (int nt = 0; nt < 4; ++nt) {
      float y = v[nt][reg] * inv;
      unsigned int hi = f2bf(y);
      size_t idx = base + (size_t)reg * 64 + nt * 16 + li;
      oh[idx] = (ushort_t)hi;
      ol[idx] = (ushort_t)f2bf(y - bf2f(hi));
    }
  }
}

// ------- fused GEMM + bf16 transpose: vt[s][c 0..63][j 0..575] (v path) -------
__global__ __launch_bounds__(256) void gemmtrans_v_k(const float* __restrict__ X,
                                                     const float* __restrict__ W,
                                                     const float* __restrict__ bias,
                                                     ushort_t* __restrict__ vt) {
  __shared__ ushort_t Xh[64][72], Xl[64][72], Wh[64][72], Wl[64][72];
  __shared__ ushort_t Vs[64 * 73];
  const int tid = threadIdx.x;
  const int w = tid >> 6, l = tid & 63, li = l & 15, lg = l >> 4;
  const int r = tid >> 2, cg = tid & 3;
  const int m0 = blockIdx.x << 6;
  const int h = blockIdx.y, n0 = h << 6;
  const float* Xp = X + (size_t)(m0 + r) * 512 + cg * 16;
  const float* Wp = W + (size_t)(n0 + r) * 512 + cg * 16;
  GEMM_BODY(Xp, Wp)
#pragma unroll
  for (int nt = 0; nt < 4; ++nt) {
    float bb = bias[n0 + nt * 16 + li];
#pragma unroll
    for (int reg = 0; reg < 4; ++reg)
      Vs[(16 * w + 4 * lg + reg) * 73 + nt * 16 + li] = (ushort_t)f2bf(acc[nt][reg] + bb);
  }
  __syncthreads();
  const int a9 = m0 >> 6;
  const int b = a9 / 9;
  const int nbase = m0 - b * 576;
  const int s = b * 8 + h;
  const int c = tid >> 2, q4 = tid & 3;
  ushort_t tmp[16];
#pragma unroll
  for (int jj = 0; jj < 16; ++jj) tmp[jj] = Vs[(q4 * 16 + jj) * 73 + c];
  ushort_t* op = vt + ((size_t)s * 64 + c) * 576 + nbase + q4 * 16;
  *(uint4*)op = *(uint4*)&tmp[0];
  *(uint4*)(op + 8) = *(uint4*)&tmp[8];
}

// ---------- simE: E[s][i][j] = bf16(exp((q.k - 1)*20)), MFMA hi/lo ----------
__global__ __launch_bounds__(256) void simE2_k(const ushort_t* __restrict__ qh,
                                               const ushort_t* __restrict__ ql,
                                               const ushort_t* __restrict__ kh,
                                               const ushort_t* __restrict__ kl,
                                               ushort_t* __restrict__ E) {
  const int s = blockIdx.x, i0 = blockIdx.y << 6, j0 = blockIdx.z << 6;
  const int tid = threadIdx.x;
  const int w = tid >> 6, l = tid & 63, li = l & 15, lg = l >> 4;
  const size_t qoff = ((size_t)s * 256 + i0 + 16 * w + li) * 64 + 8 * lg;
  short8 aH0 = *(const short8*)(qh + qoff), aH1 = *(const short8*)(qh + qoff + 32);
  short8 aL0 = *(const short8*)(ql + qoff), aL1 = *(const short8*)(ql + qoff + 32);
  f32x4 acc[4] = {};
#pragma unroll
  for (int nt = 0; nt < 4; ++nt) {
    const size_t koff = ((size_t)s * 576 + j0 + nt * 16 + li) * 64 + 8 * lg;
    short8 bH0 = *(const short8*)(kh + koff), bH1 = *(const short8*)(kh + koff + 32);
    short8 bL0 = *(const short8*)(kl + koff), bL1 = *(const short8*)(kl + koff + 32);
    acc[nt] = __builtin_amdgcn_mfma_f32_16x16x32_bf16(aH0, bH0, acc[nt], 0, 0, 0);
    acc[nt] = __builtin_amdgcn_mfma_f32_16x16x32_bf16(aH1, bH1, acc[nt], 0, 0, 0);
    acc[nt] = __builtin_amdgcn_mfma_f32_16x16x32_bf16(aH0, bL0, acc[nt], 0, 0, 0);
    acc[nt] = __builtin_amdgcn_mfma_f32_16x16x32_bf16(aH1, bL1, acc[nt], 0, 0, 0);
    acc[nt] = __builtin_amdgcn_mfma_f32_16x16x32_bf16(aL0, bH0, acc[nt], 0, 0, 0);
    acc[nt] = __builtin_amdgcn_mfma_f32_16x16x32_bf16(aL1, bH1, acc[nt], 0, 0, 0);
  }
  ushort_t* Ep = E + (size_t)s * 147456;
#pragma unroll
  for (int nt = 0; nt < 4; ++nt)
#pragma unroll
    for (int reg = 0; reg < 4; ++reg) {
      float e = __expf((acc[nt][reg] - 1.0f) * INV_EPS);
      Ep[(size_t)(i0 + 16 * w + 4 * lg + reg) * 576 + j0 + nt * 16 + li] = (ushort_t)f2bf(e);
    }
}

// ---------------- Sinkhorn v6: role-swapped matvec1 (4 B-reads/wave), overlapped exchange ----------------
// Wave w holds: A-layout E frags for k-tile w across all 8 row-tiles (+1 extra tile from
// k-tiles 16/17), and B-layout frags (unchanged). matvec1 = MFMA(A=bv_frag, B=E_A-frag):
// contraction stays on E's column axis, so one bv read serves 8 row-tiles.
// Order: matvec2 -> bar -> publish colsums (MALL) -> matvec1 (hides round trip) -> bar ->
// u-update || poll+v-update -> bar.  Parity double-buffer + tag polling as v5.
#define SK_SMEM 147456

__global__ __launch_bounds__(1024, 1) void sinkhorn6_k(const ushort_t* __restrict__ E,
                                                       float* __restrict__ gA,
                                                       float* __restrict__ gB,
                                                       unsigned long long* __restrict__ gpart,
                                                       float C_mu, float C_nu) {
  extern __shared__ char smem[];
  const int g = blockIdx.x, s = g >> 1, rh = g & 1, pg = g ^ 1;
  const int tid = threadIdx.x, w = tid >> 6, l = tid & 63, li = l & 15, lg = l >> 4;
  unsigned long long* myP = gpart + (size_t)g * 1152;
  const unsigned long long* prP = gpart + (size_t)pg * 1152;

  // ---- stage E half (bf16) into LDS ----
  ushort_t* Elds = (ushort_t*)smem;  // [128][576]
  {
    const uint4* Eg = (const uint4*)(E + (size_t)s * 147456 + (size_t)rh * 73728);
    uint4* El4 = (uint4*)Elds;
    for (int idx = tid; idx < 9216; idx += 1024) El4[idx] = Eg[idx];
  }
  __syncthreads();

  // A-layout frags: tiles (rt=0..7, kt=w) + extra (rtx, ktx)
  short8 afr[9];
#pragma unroll
  for (int rt = 0; rt < 8; ++rt)
    afr[rt] = *(const short8*)(Elds + (rt * 16 + li) * 576 + w * 32 + 8 * lg);
  const int rtx = w & 7, ktx = 16 + (w >> 3);
  afr[8] = *(const short8*)(Elds + (rtx * 16 + li) * 576 + ktx * 32 + 8 * lg);
  // B-layout frags (as v5)
  const int ktB = w >> 2, ntb = (w & 3) * 9;
  short8 bfr[9];
#pragma unroll
  for (int p9 = 0; p9 < 9; ++p9) {
    const ushort_t* p = Elds + (ktB * 32 + 8 * lg) * 576 + (ntb + p9) * 16 + li;
    Pk pk;
    pk.u.x = (unsigned int)p[0]    | ((unsigned int)p[576]  << 16);
    pk.u.y = (unsigned int)p[1152] | ((unsigned int)p[1728] << 16);
    pk.u.z = (unsigned int)p[2304] | ((unsigned int)p[2880] << 16);
    pk.u.w = (unsigned int)p[3456] | ((unsigned int)p[4032] << 16);
    bfr[p9] = pk.s;
  }
  __syncthreads();

  // ---- overlay scratch ----
  float* uu = (float*)smem;                        // 128
  float* vv = uu + 128;                            // 576
  unsigned int* au_h = (unsigned int*)(vv + 576);  // 64 (128 bf16 pairs)
  unsigned int* au_l = au_h + 64;                  // 64
  unsigned int* bv_h = au_l + 64;                  // 288
  unsigned int* bv_l = bv_h + 288;                 // 288
  float* rpart = (float*)(bv_l + 288);             // [18][128]
  float* colp = rpart + 2304;                      // [4][576]
  float* cso = colp + 2304;                        // 576
  ushort_t* au_hs = (ushort_t*)au_h;
  ushort_t* au_ls = (ushort_t*)au_l;
  ushort_t* bv_hs = (ushort_t*)bv_h;
  ushort_t* bv_ls = (ushort_t*)bv_l;

  if (tid < 64) { au_h[tid] = 0x3F803F80u; au_l[tid] = 0u; }
  if (tid < 288) { bv_h[tid] = 0x3F803F80u; bv_l[tid] = 0u; }
  __syncthreads();

  for (int t = 0; t < 100; ++t) {
    // ---- matvec2: col partials (uses OLD au) ----
    {
      Pk ah, al;
      ah.u = *(const uint4*)&au_h[ktB * 16 + 4 * lg];
      al.u = *(const uint4*)&au_l[ktB * 16 + 4 * lg];
      float* cp = colp + (w >> 2) * 576;
#pragma unroll
      for (int p9 = 0; p9 < 9; ++p9) {
        f32x4 a2 = {0.f, 0.f, 0.f, 0.f};
        a2 = __builtin_amdgcn_mfma_f32_16x16x32_bf16(ah.s, bfr[p9], a2, 0, 0, 0);
        a2 = __builtin_amdgcn_mfma_f32_16x16x32_bf16(al.s, bfr[p9], a2, 0, 0, 0);
        if (l < 16) cp[(ntb + p9) * 16 + l] = a2[0];
      }
    }
    __syncthreads();
    const int par = t & 1;
    // ---- publish colsums to partner (then fall through to matvec1) ----
    if (tid < 576) {
      float cs = colp[tid] + colp[576 + tid] + colp[1152 + tid] + colp[1728 + tid];
      cso[tid] = cs;
      unsigned long long pv = (unsigned long long)__float_as_uint(cs) |
                              ((unsigned long long)(unsigned int)(t + 1) << 32);
      __hip_atomic_store(&myP[par * 576 + tid], pv, __ATOMIC_RELAXED, __HIP_MEMORY_SCOPE_AGENT);
    }
    // ---- matvec1: row partials (uses OLD bv); hides the MALL round trip ----
    {
      Pk bh, bl, bhx, blx;
      bh.u = *(const uint4*)&bv_h[w * 16 + 4 * lg];
      bl.u = *(const uint4*)&bv_l[w * 16 + 4 * lg];
      bhx.u = *(const uint4*)&bv_h[ktx * 16 + 4 * lg];
      blx.u = *(const uint4*)&bv_l[ktx * 16 + 4 * lg];
#pragma unroll
      for (int rt = 0; rt < 8; ++rt) {
        f32x4 a1 = {0.f, 0.f, 0.f, 0.f};
        a1 = __builtin_amdgcn_mfma_f32_16x16x32_bf16(bh.s, afr[rt], a1, 0, 0, 0);
        a1 = __builtin_amdgcn_mfma_f32_16x16x32_bf16(bl.s, afr[rt], a1, 0, 0, 0);
        if (l < 16) rpart[w * 128 + rt * 16 + l] = a1[0];
      }
      f32x4 a1 = {0.f, 0.f, 0.f, 0.f};
      a1 = __builtin_amdgcn_mfma_f32_16x16x32_bf16(bhx.s, afr[8], a1, 0, 0, 0);
      a1 = __builtin_amdgcn_mfma_f32_16x16x32_bf16(blx.s, afr[8], a1, 0, 0, 0);
      if (l < 16) rpart[ktx * 128 + rtx * 16 + l] = a1[0];
    }
    __syncthreads();
    // ---- u-update (tid<128) || poll partner + v-update (tid 128..703) ----
    if (tid < 128) {
      float rs = 0.0f;
#pragma unroll
      for (int kc = 0; kc < 18; ++kc) rs += rpart[kc * 128 + tid];
      float un = C_mu - EPS_OT * __logf(rs);
      uu[tid] = un;
      float a = __expf(fminf(fmaxf(un * INV_EPS, -80.f), 80.f));
      unsigned int hi = f2bf(a);
      au_hs[tid] = (ushort_t)hi;
      au_ls[tid] = (ushort_t)f2bf(a - bf2f(hi));
    } else if (tid < 704) {
      const int j = tid - 128;
      const unsigned int tg = (unsigned int)(t + 1);
      unsigned long long p0;
      for (;;) {
        p0 = __hip_atomic_load(&prP[par * 576 + j], __ATOMIC_RELAXED, __HIP_MEMORY_SCOPE_AGENT);
        if ((unsigned int)(p0 >> 32) == tg) break;
        __builtin_amdgcn_s_sleep(1);
      }
      float tot = cso[j] + __uint_as_float((unsigned int)p0);
      float vn = C_nu - EPS_OT * __logf(tot);
      vv[j] = vn;
      float bb = __expf(fminf(fmaxf(vn * INV_EPS, -80.f), 80.f));
      unsigned int hi = f2bf(bb);
      bv_hs[j] = (ushort_t)hi;
      bv_ls[j] = (ushort_t)f2bf(bb - bf2f(hi));
    }
    __syncthreads();
  }
  if (tid < 128) gA[(size_t)s * 256 + rh * 128 + tid] = uu[tid] * INV_EPS;
  if (rh == 0 && tid < 576) gB[(size_t)s * 576 + tid] = vv[tid] * INV_EPS + 11.9012851f;  // +ln(147456)
}

// ---------- scorev: out = score @ V via MFMA (hi/lo P, bf16 V from vt) ----------
__global__ __launch_bounds__(256) void scorev2_k(const ushort_t* __restrict__ E,
                                                 const ushort_t* __restrict__ vt,
                                                 const float* __restrict__ gA,
                                                 const float* __restrict__ gB,
                                                 float* __restrict__ Y) {
  __shared__ float gBs[576];
  const int s = blockIdx.x, i0 = blockIdx.y << 6;
  const int tid = threadIdx.x;
  const int w = tid >> 6, l = tid & 63, li = l & 15, lg = l >> 4;
  for (int j = tid; j < 576; j += 256) gBs[j] = gB[(size_t)s * 576 + j];
  const float ga = gA[(size_t)s * 256 + i0 + 16 * w + li];
  const ushort_t* Erow = E + (size_t)s * 147456 + (size_t)(i0 + 16 * w + li) * 576;
  f32x4 acc[4] = {};
  __syncthreads();
  for (int kst = 0; kst < 18; ++kst) {
    const int jb = kst * 32 + 8 * lg;
    Pk eu; eu.u = *(const uint4*)(Erow + jb);
    float pv[8], pl8[8];
#pragma unroll
    for (int jj = 0; jj < 8; ++jj) {
      unsigned int us = (unsigned int)(unsigned short)eu.s[jj];
      float e = bf2f(us);
      float le = __logf(e);
      pv[jj] = (1.0f + EPS_OT * le) * __expf(le + ga + gBs[jb + jj]);
    }
    Pk ph, pl;
#pragma unroll
    for (int jj = 0; jj < 8; ++jj) {
      unsigned int h = f2bf(pv[jj]);
      ((unsigned short*)&ph.s)[jj] = (unsigned short)h;
      pl8[jj] = pv[jj] - bf2f(h);
    }
#pragma unroll
    for (int jj = 0; jj < 8; ++jj)
      ((unsigned short*)&pl.s)[jj] = (unsigned short)f2bf(pl8[jj]);
#pragma unroll
    for (int nt = 0; nt < 4; ++nt) {
      Pk vf; vf.u = *(const uint4*)(vt + ((size_t)s * 64 + nt * 16 + li) * 576 + jb);
      acc[nt] = __builtin_amdgcn_mfma_f32_16x16x32_bf16(ph.s, vf.s, acc[nt], 0, 0, 0);
      acc[nt] = __builtin_amdgcn_mfma_f32_16x16x32_bf16(pl.s, vf.s, acc[nt], 0, 0, 0);
    }
  }
  const int b = s >> 3, h = s & 7;
#pragma unroll
  for (int nt = 0; nt < 4; ++nt)
#pragma unroll
    for (int reg = 0; reg < 4; ++reg)
      Y[((size_t)(b * 256 + i0 + 16 * w + 4 * lg + reg) << 9) + (h << 6) + nt * 16 + li] =
          acc[nt][reg];
}

// ------------------------- final row l2norm (plain division) -------------------------
__global__ __launch_bounds__(256) void rownorm_k(const float* __restrict__ X,
                                                 float* __restrict__ out) {
  const size_t row = blockIdx.x;
  const int tid = threadIdx.x;
  float x0 = X[(row << 9) + tid], x1 = X[(row << 9) + 256 + tid];
  float st = fmaf(x0, x0, x1 * x1);
#pragma unroll
  for (int off = 32; off; off >>= 1) st += __shfl_xor(st, off, 64);
  __shared__ float ps[4];
  if ((tid & 63) == 0) ps[tid >> 6] = st;
  __syncthreads();
  const float inv = 1.0f / sqrtf(ps[0] + ps[1] + ps[2] + ps[3]);
  out[(row << 9) + tid] = x0 * inv;
  out[(row << 9) + 256 + tid] = x1 * inv;
}

extern "C" void kernel_launch(void* const* d_in, const int* in_sizes, int n_in,
                              void* d_out, int out_size, void* d_ws, size_t ws_size,
                              hipStream_t stream) {
  const float* F_t = (const float*)d_in[0];
  const float* F_s = (const float*)d_in[1];
  const float* Wq = (const float*)d_in[2];
  const float* bq = (const float*)d_in[3];
  const float* Wk = (const float*)d_in[4];
  const float* bk = (const float*)d_in[5];
  const float* Wv = (const float*)d_in[6];
  const float* bvb = (const float*)d_in[7];
  const float* Wp = (const float*)d_in[8];
  const float* bp = (const float*)d_in[9];
  float* out = (float*)d_out;
  float* ws = (float*)d_ws;

  float* T0 = ws;                            // 2,097,152 f32 (scorev out)
  float* T1 = T0 + 2097152;                  // 2,097,152 f32
  ushort_t* qh = (ushort_t*)(T1 + 2097152);  // 2,097,152 us
  ushort_t* ql = qh + 2097152;               // 2,097,152
  ushort_t* kh = ql + 2097152;               // 4,718,592
  ushort_t* kl = kh + 4718592;               // 4,718,592
  ushort_t* vt = kl + 4718592;               // 4,718,592  [128][64][576]
  ushort_t* Eb = vt + 4718592;               // 18,874,368 [128][256][576]
  float* gA = (float*)(Eb + 18874368);       // 32,768
  float* gB = gA + 32768;                    // 73,728
  unsigned long long* gpart = (unsigned long long*)(gB + 73728);  // 256*1152 ull

  const float C_mu = (float)(0.05 * log(1.0 / 256.0 + 1e-8));
  const float C_nu = (float)(0.05 * log(1.0 / 576.0 + 1e-8));

  (void)hipFuncSetAttribute((const void*)sinkhorn6_k,
                            hipFuncAttributeMaxDynamicSharedMemorySize, SK_SMEM);

  gemmnorm_k<<<dim3(64, 8), 256, 0, stream>>>(F_t, Wq, bq, qh, ql, 256);
  gemmnorm_k<<<dim3(144, 8), 256, 0, stream>>>(F_s, Wk, bk, kh, kl, 576);
  gemmtrans_v_k<<<dim3(144, 8), 256, 0, stream>>>(F_s, Wv, bvb, vt);
  simE2_k<<<dim3(128, 4, 9), 256, 0, stream>>>(qh, ql, kh, kl, Eb);
  sinkhorn6_k<<<256, 1024, SK_SMEM, stream>>>(Eb, gA, gB, gpart, C_mu, C_nu);
  scorev2_k<<<dim3(128, 4), 256, 0, stream>>>(Eb, vt, gA, gB, T0);
  gemm_bf16_k<<<dim3(64, 8), 256, 0, stream>>>(T0, Wp, bp, T1, 4096);
  rownorm_k<<<4096, 256, 0, stream>>>(T1, out);
}

// Round 7
// 430.310 us; speedup vs baseline: 10.6152x; 1.0872x over previous
//
#include <hip/hip_runtime.h>
#include <math.h>

#define EPS_OT 0.05f
#define INV_EPS 20.0f

typedef unsigned short ushort_t;
typedef __attribute__((ext_vector_type(8))) short short8;
typedef __attribute__((ext_vector_type(4))) float f32x4;
union Pk { uint4 u; short8 s; };

__device__ __forceinline__ unsigned int f2bf(float f) {  // RNE f32->bf16
  unsigned int u = __float_as_uint(f);
  return (u + 0x7FFFu + ((u >> 16) & 1u)) >> 16;
}
__device__ __forceinline__ float bf2f(unsigned int u) { return __uint_as_float(u << 16); }

// ---------------- pack: fp32 -> hi/lo bf16 (one-time; removes conversions from GEMMs) ----------------
__global__ __launch_bounds__(256) void pack_k(const float* __restrict__ F_t,
                                              const float* __restrict__ F_s,
                                              const float* __restrict__ Wq,
                                              const float* __restrict__ Wk,
                                              const float* __restrict__ Wv,
                                              const float* __restrict__ Wp,
                                              ushort_t* __restrict__ Fth, ushort_t* __restrict__ Ftl,
                                              ushort_t* __restrict__ Fsh, ushort_t* __restrict__ Fsl,
                                              ushort_t* __restrict__ Wqh, ushort_t* __restrict__ Wql,
                                              ushort_t* __restrict__ Wkh, ushort_t* __restrict__ Wkl,
                                              ushort_t* __restrict__ Wvh, ushort_t* __restrict__ Wvl,
                                              ushort_t* __restrict__ Wph) {
  const int blk = blockIdx.x;
  const float* src; ushort_t* dh; ushort_t* dl; size_t off;
  if (blk < 2048)      { src = F_t; dh = Fth; dl = Ftl; off = (size_t)blk * 1024; }
  else if (blk < 6656) { src = F_s; dh = Fsh; dl = Fsl; off = (size_t)(blk - 2048) * 1024; }
  else if (blk < 6912) { src = Wq;  dh = Wqh; dl = Wql; off = (size_t)(blk - 6656) * 1024; }
  else if (blk < 7168) { src = Wk;  dh = Wkh; dl = Wkl; off = (size_t)(blk - 6912) * 1024; }
  else if (blk < 7424) { src = Wv;  dh = Wvh; dl = Wvl; off = (size_t)(blk - 7168) * 1024; }
  else                 { src = Wp;  dh = Wph; dl = nullptr; off = (size_t)(blk - 7424) * 1024; }
  const size_t i = off + (size_t)threadIdx.x * 4;
  float4 f = *(const float4*)(src + i);
  unsigned int h0 = f2bf(f.x), h1 = f2bf(f.y), h2 = f2bf(f.z), h3 = f2bf(f.w);
  uint2 hh; hh.x = h0 | (h1 << 16); hh.y = h2 | (h3 << 16);
  *(uint2*)(dh + i) = hh;
  if (dl) {
    uint2 ll;
    ll.x = f2bf(f.x - bf2f(h0)) | (f2bf(f.y - bf2f(h1)) << 16);
    ll.y = f2bf(f.z - bf2f(h2)) | (f2bf(f.w - bf2f(h3)) << 16);
    *(uint2*)(dl + i) = ll;
  }
}

// ====== hi/lo GEMM main loop on pre-packed bf16 (64x64 tile, K=512, 3-MFMA) ======
#define GEMM_HL_BODY()                                                                      \
  f32x4 acc[4] = {};                                                                        \
  for (int k0 = 0; k0 < 512; k0 += 64) {                                                    \
    uint4 a0 = *(const uint4*)(Xp_h + k0), a1 = *(const uint4*)(Xp_h + k0 + 8);             \
    uint4 b0 = *(const uint4*)(Xp_l + k0), b1 = *(const uint4*)(Xp_l + k0 + 8);             \
    uint4 c0 = *(const uint4*)(Wp_h + k0), c1 = *(const uint4*)(Wp_h + k0 + 8);             \
    uint4 d0 = *(const uint4*)(Wp_l + k0), d1 = *(const uint4*)(Wp_l + k0 + 8);             \
    __syncthreads();                                                                        \
    *(uint4*)&Xh[r][cg * 16] = a0; *(uint4*)&Xh[r][cg * 16 + 8] = a1;                       \
    *(uint4*)&Xl[r][cg * 16] = b0; *(uint4*)&Xl[r][cg * 16 + 8] = b1;                       \
    *(uint4*)&Wh[r][cg * 16] = c0; *(uint4*)&Wh[r][cg * 16 + 8] = c1;                       \
    *(uint4*)&Wl[r][cg * 16] = d0; *(uint4*)&Wl[r][cg * 16 + 8] = d1;                       \
    __syncthreads();                                                                        \
    _Pragma("unroll") for (int kst = 0; kst < 2; ++kst) {                                   \
      short8 ah = *(const short8*)&Xh[16 * w + li][kst * 32 + 8 * lg];                      \
      short8 al = *(const short8*)&Xl[16 * w + li][kst * 32 + 8 * lg];                      \
      _Pragma("unroll") for (int nt = 0; nt < 4; ++nt) {                                    \
        short8 bh = *(const short8*)&Wh[nt * 16 + li][kst * 32 + 8 * lg];                   \
        short8 bl = *(const short8*)&Wl[nt * 16 + li][kst * 32 + 8 * lg];                   \
        acc[nt] = __builtin_amdgcn_mfma_f32_16x16x32_bf16(ah, bh, acc[nt], 0, 0, 0);        \
        acc[nt] = __builtin_amdgcn_mfma_f32_16x16x32_bf16(ah, bl, acc[nt], 0, 0, 0);        \
        acc[nt] = __builtin_amdgcn_mfma_f32_16x16x32_bf16(al, bh, acc[nt], 0, 0, 0);        \
      }                                                                                     \
    }                                                                                       \
  }

// ====== plain bf16 GEMM main loop (64x64 tile, K=512, 1-MFMA) ======
#define GEMM_PL_BODY()                                                                      \
  f32x4 acc[4] = {};                                                                        \
  for (int k0 = 0; k0 < 512; k0 += 64) {                                                    \
    uint4 a0 = *(const uint4*)(Xp_h + k0), a1 = *(const uint4*)(Xp_h + k0 + 8);             \
    uint4 c0 = *(const uint4*)(Wp_h + k0), c1 = *(const uint4*)(Wp_h + k0 + 8);             \
    __syncthreads();                                                                        \
    *(uint4*)&Xh[r][cg * 16] = a0; *(uint4*)&Xh[r][cg * 16 + 8] = a1;                       \
    *(uint4*)&Wh[r][cg * 16] = c0; *(uint4*)&Wh[r][cg * 16 + 8] = c1;                       \
    __syncthreads();                                                                        \
    _Pragma("unroll") for (int kst = 0; kst < 2; ++kst) {                                   \
      short8 ah = *(const short8*)&Xh[16 * w + li][kst * 32 + 8 * lg];                      \
      _Pragma("unroll") for (int nt = 0; nt < 4; ++nt) {                                    \
        short8 bh = *(const short8*)&Wh[nt * 16 + li][kst * 32 + 8 * lg];                   \
        acc[nt] = __builtin_amdgcn_mfma_f32_16x16x32_bf16(ah, bh, acc[nt], 0, 0, 0);        \
      }                                                                                     \
    }                                                                                       \
  }

// ------- fused GEMM + per-head l2norm -> hi/lo bf16 [B*H][Nn][64] (q and k) -------
__global__ __launch_bounds__(256) void gemmnorm2_k(const ushort_t* __restrict__ Xg_h,
                                                   const ushort_t* __restrict__ Xg_l,
                                                   const ushort_t* __restrict__ Wg_h,
                                                   const ushort_t* __restrict__ Wg_l,
                                                   const float* __restrict__ bias,
                                                   ushort_t* __restrict__ oh,
                                                   ushort_t* __restrict__ ol, int Nn) {
  __shared__ ushort_t Xh[64][72], Xl[64][72], Wh[64][72], Wl[64][72];
  const int tid = threadIdx.x;
  const int w = tid >> 6, l = tid & 63, li = l & 15, lg = l >> 4;
  const int r = tid >> 2, cg = tid & 3;
  const int m0 = blockIdx.x << 6;
  const int h = blockIdx.y, n0 = h << 6;
  const ushort_t* Xp_h = Xg_h + (size_t)(m0 + r) * 512 + cg * 16;
  const ushort_t* Xp_l = Xg_l + (size_t)(m0 + r) * 512 + cg * 16;
  const ushort_t* Wp_h = Wg_h + (size_t)(n0 + r) * 512 + cg * 16;
  const ushort_t* Wp_l = Wg_l + (size_t)(n0 + r) * 512 + cg * 16;
  GEMM_HL_BODY()
  float v[4][4];
  float ss[4] = {0.f, 0.f, 0.f, 0.f};
#pragma unroll
  for (int nt = 0; nt < 4; ++nt) {
    float bb = bias[n0 + nt * 16 + li];
#pragma unroll
    for (int reg = 0; reg < 4; ++reg) {
      float y = acc[nt][reg] + bb;
      v[nt][reg] = y;
      ss[reg] = fmaf(y, y, ss[reg]);
    }
  }
#pragma unroll
  for (int off = 1; off < 16; off <<= 1)
#pragma unroll
    for (int reg = 0; reg < 4; ++reg) ss[reg] += __shfl_xor(ss[reg], off, 64);
  const int b = m0 / Nn;
  const int nbase = m0 - b * Nn;
  const size_t base = ((size_t)(b * 8 + h) * Nn + nbase + 16 * w + 4 * lg) * 64;
#pragma unroll
  for (int reg = 0; reg < 4; ++reg) {
    float inv = 1.0f / fmaxf(sqrtf(ss[reg]), 1e-12f);
#pragma unroll
    for (int nt = 0; nt < 4; ++nt) {
      float y = v[nt][reg] * inv;
      unsigned int hi = f2bf(y);
      size_t idx = base + (size_t)reg * 64 + nt * 16 + li;
      oh[idx] = (ushort_t)hi;
      ol[idx] = (ushort_t)f2bf(y - bf2f(hi));
    }
  }
}

// ------- fused plain-bf16 GEMM + transpose: vt[s][c 0..63][j 0..575] (v path) -------
__global__ __launch_bounds__(256) void gemmtrans2_k(const ushort_t* __restrict__ Xg_h,
                                                    const ushort_t* __restrict__ Wg_h,
                                                    const float* __restrict__ bias,
                                                    ushort_t* __restrict__ vt) {
  __shared__ ushort_t Xh[64][72], Wh[64][72];
  __shared__ ushort_t Vs[64 * 73];
  const int tid = threadIdx.x;
  const int w = tid >> 6, l = tid & 63, li = l & 15, lg = l >> 4;
  const int r = tid >> 2, cg = tid & 3;
  const int m0 = blockIdx.x << 6;
  const int h = blockIdx.y, n0 = h << 6;
  const ushort_t* Xp_h = Xg_h + (size_t)(m0 + r) * 512 + cg * 16;
  const ushort_t* Wp_h = Wg_h + (size_t)(n0 + r) * 512 + cg * 16;
  GEMM_PL_BODY()
#pragma unroll
  for (int nt = 0; nt < 4; ++nt) {
    float bb = bias[n0 + nt * 16 + li];
#pragma unroll
    for (int reg = 0; reg < 4; ++reg)
      Vs[(16 * w + 4 * lg + reg) * 73 + nt * 16 + li] = (ushort_t)f2bf(acc[nt][reg] + bb);
  }
  __syncthreads();
  const int a9 = m0 >> 6;
  const int b = a9 / 9;
  const int nbase = m0 - b * 576;
  const int s = b * 8 + h;
  const int c = tid >> 2, q4 = tid & 3;
  ushort_t tmp[16];
#pragma unroll
  for (int jj = 0; jj < 16; ++jj) tmp[jj] = Vs[(q4 * 16 + jj) * 73 + c];
  ushort_t* op = vt + ((size_t)s * 64 + c) * 576 + nbase + q4 * 16;
  *(uint4*)op = *(uint4*)&tmp[0];
  *(uint4*)(op + 8) = *(uint4*)&tmp[8];
}

// ------- final plain-bf16 GEMM (scorev-out bf16 @ Wp_h) -> fp32 -------
__global__ __launch_bounds__(256) void gemmplain_k(const ushort_t* __restrict__ Xg_h,
                                                   const ushort_t* __restrict__ Wg_h,
                                                   const float* __restrict__ bias,
                                                   float* __restrict__ Y) {
  __shared__ ushort_t Xh[64][72], Wh[64][72];
  const int tid = threadIdx.x;
  const int w = tid >> 6, l = tid & 63, li = l & 15, lg = l >> 4;
  const int r = tid >> 2, cg = tid & 3;
  const int m0 = blockIdx.x << 6, n0 = blockIdx.y << 6;
  const ushort_t* Xp_h = Xg_h + (size_t)(m0 + r) * 512 + cg * 16;
  const ushort_t* Wp_h = Wg_h + (size_t)(n0 + r) * 512 + cg * 16;
  GEMM_PL_BODY()
#pragma unroll
  for (int nt = 0; nt < 4; ++nt) {
    float bb = bias[n0 + nt * 16 + li];
#pragma unroll
    for (int reg = 0; reg < 4; ++reg)
      Y[(size_t)(m0 + 16 * w + 4 * lg + reg) * 512 + n0 + nt * 16 + li] = acc[nt][reg] + bb;
  }
}

// ---------- simE: E[s][i][j] = bf16(exp((q.k - 1)*20)), MFMA hi/lo ----------
__global__ __launch_bounds__(256) void simE2_k(const ushort_t* __restrict__ qh,
                                               const ushort_t* __restrict__ ql,
                                               const ushort_t* __restrict__ kh,
                                               const ushort_t* __restrict__ kl,
                                               ushort_t* __restrict__ E) {
  const int s = blockIdx.x, i0 = blockIdx.y << 6, j0 = blockIdx.z << 6;
  const int tid = threadIdx.x;
  const int w = tid >> 6, l = tid & 63, li = l & 15, lg = l >> 4;
  const size_t qoff = ((size_t)s * 256 + i0 + 16 * w + li) * 64 + 8 * lg;
  short8 aH0 = *(const short8*)(qh + qoff), aH1 = *(const short8*)(qh + qoff + 32);
  short8 aL0 = *(const short8*)(ql + qoff), aL1 = *(const short8*)(ql + qoff + 32);
  f32x4 acc[4] = {};
#pragma unroll
  for (int nt = 0; nt < 4; ++nt) {
    const size_t koff = ((size_t)s * 576 + j0 + nt * 16 + li) * 64 + 8 * lg;
    short8 bH0 = *(const short8*)(kh + koff), bH1 = *(const short8*)(kh + koff + 32);
    short8 bL0 = *(const short8*)(kl + koff), bL1 = *(const short8*)(kl + koff + 32);
    acc[nt] = __builtin_amdgcn_mfma_f32_16x16x32_bf16(aH0, bH0, acc[nt], 0, 0, 0);
    acc[nt] = __builtin_amdgcn_mfma_f32_16x16x32_bf16(aH1, bH1, acc[nt], 0, 0, 0);
    acc[nt] = __builtin_amdgcn_mfma_f32_16x16x32_bf16(aH0, bL0, acc[nt], 0, 0, 0);
    acc[nt] = __builtin_amdgcn_mfma_f32_16x16x32_bf16(aH1, bL1, acc[nt], 0, 0, 0);
    acc[nt] = __builtin_amdgcn_mfma_f32_16x16x32_bf16(aL0, bH0, acc[nt], 0, 0, 0);
    acc[nt] = __builtin_amdgcn_mfma_f32_16x16x32_bf16(aL1, bH1, acc[nt], 0, 0, 0);
  }
  ushort_t* Ep = E + (size_t)s * 147456;
#pragma unroll
  for (int nt = 0; nt < 4; ++nt)
#pragma unroll
    for (int reg = 0; reg < 4; ++reg) {
      float e = __expf((acc[nt][reg] - 1.0f) * INV_EPS);
      Ep[(size_t)(i0 + 16 * w + 4 * lg + reg) * 576 + j0 + nt * 16 + li] = (ushort_t)f2bf(e);
    }
}

// ---------------- Sinkhorn v6 (unchanged from R6) ----------------
#define SK_SMEM 147456

__global__ __launch_bounds__(1024, 1) void sinkhorn6_k(const ushort_t* __restrict__ E,
                                                       float* __restrict__ gA,
                                                       float* __restrict__ gB,
                                                       unsigned long long* __restrict__ gpart,
                                                       float C_mu, float C_nu) {
  extern __shared__ char smem[];
  const int g = blockIdx.x, s = g >> 1, rh = g & 1, pg = g ^ 1;
  const int tid = threadIdx.x, w = tid >> 6, l = tid & 63, li = l & 15, lg = l >> 4;
  unsigned long long* myP = gpart + (size_t)g * 1152;
  const unsigned long long* prP = gpart + (size_t)pg * 1152;

  ushort_t* Elds = (ushort_t*)smem;  // [128][576]
  {
    const uint4* Eg = (const uint4*)(E + (size_t)s * 147456 + (size_t)rh * 73728);
    uint4* El4 = (uint4*)Elds;
    for (int idx = tid; idx < 9216; idx += 1024) El4[idx] = Eg[idx];
  }
  __syncthreads();

  short8 afr[9];
#pragma unroll
  for (int rt = 0; rt < 8; ++rt)
    afr[rt] = *(const short8*)(Elds + (rt * 16 + li) * 576 + w * 32 + 8 * lg);
  const int rtx = w & 7, ktx = 16 + (w >> 3);
  afr[8] = *(const short8*)(Elds + (rtx * 16 + li) * 576 + ktx * 32 + 8 * lg);
  const int ktB = w >> 2, ntb = (w & 3) * 9;
  short8 bfr[9];
#pragma unroll
  for (int p9 = 0; p9 < 9; ++p9) {
    const ushort_t* p = Elds + (ktB * 32 + 8 * lg) * 576 + (ntb + p9) * 16 + li;
    Pk pk;
    pk.u.x = (unsigned int)p[0]    | ((unsigned int)p[576]  << 16);
    pk.u.y = (unsigned int)p[1152] | ((unsigned int)p[1728] << 16);
    pk.u.z = (unsigned int)p[2304] | ((unsigned int)p[2880] << 16);
    pk.u.w = (unsigned int)p[3456] | ((unsigned int)p[4032] << 16);
    bfr[p9] = pk.s;
  }
  __syncthreads();

  float* uu = (float*)smem;                        // 128
  float* vv = uu + 128;                            // 576
  unsigned int* au_h = (unsigned int*)(vv + 576);  // 64
  unsigned int* au_l = au_h + 64;                  // 64
  unsigned int* bv_h = au_l + 64;                  // 288
  unsigned int* bv_l = bv_h + 288;                 // 288
  float* rpart = (float*)(bv_l + 288);             // [18][128]
  float* colp = rpart + 2304;                      // [4][576]
  float* cso = colp + 2304;                        // 576
  ushort_t* au_hs = (ushort_t*)au_h;
  ushort_t* au_ls = (ushort_t*)au_l;
  ushort_t* bv_hs = (ushort_t*)bv_h;
  ushort_t* bv_ls = (ushort_t*)bv_l;

  if (tid < 64) { au_h[tid] = 0x3F803F80u; au_l[tid] = 0u; }
  if (tid < 288) { bv_h[tid] = 0x3F803F80u; bv_l[tid] = 0u; }
  __syncthreads();

  for (int t = 0; t < 100; ++t) {
    {
      Pk ah, al;
      ah.u = *(const uint4*)&au_h[ktB * 16 + 4 * lg];
      al.u = *(const uint4*)&au_l[ktB * 16 + 4 * lg];
      float* cp = colp + (w >> 2) * 576;
#pragma unroll
      for (int p9 = 0; p9 < 9; ++p9) {
        f32x4 a2 = {0.f, 0.f, 0.f, 0.f};
        a2 = __builtin_amdgcn_mfma_f32_16x16x32_bf16(ah.s, bfr[p9], a2, 0, 0, 0);
        a2 = __builtin_amdgcn_mfma_f32_16x16x32_bf16(al.s, bfr[p9], a2, 0, 0, 0);
        if (l < 16) cp[(ntb + p9) * 16 + l] = a2[0];
      }
    }
    __syncthreads();
    const int par = t & 1;
    if (tid < 576) {
      float cs = colp[tid] + colp[576 + tid] + colp[1152 + tid] + colp[1728 + tid];
      cso[tid] = cs;
      unsigned long long pv = (unsigned long long)__float_as_uint(cs) |
                              ((unsigned long long)(unsigned int)(t + 1) << 32);
      __hip_atomic_store(&myP[par * 576 + tid], pv, __ATOMIC_RELAXED, __HIP_MEMORY_SCOPE_AGENT);
    }
    {
      Pk bh, bl, bhx, blx;
      bh.u = *(const uint4*)&bv_h[w * 16 + 4 * lg];
      bl.u = *(const uint4*)&bv_l[w * 16 + 4 * lg];
      bhx.u = *(const uint4*)&bv_h[ktx * 16 + 4 * lg];
      blx.u = *(const uint4*)&bv_l[ktx * 16 + 4 * lg];
#pragma unroll
      for (int rt = 0; rt < 8; ++rt) {
        f32x4 a1 = {0.f, 0.f, 0.f, 0.f};
        a1 = __builtin_amdgcn_mfma_f32_16x16x32_bf16(bh.s, afr[rt], a1, 0, 0, 0);
        a1 = __builtin_amdgcn_mfma_f32_16x16x32_bf16(bl.s, afr[rt], a1, 0, 0, 0);
        if (l < 16) rpart[w * 128 + rt * 16 + l] = a1[0];
      }
      f32x4 a1 = {0.f, 0.f, 0.f, 0.f};
      a1 = __builtin_amdgcn_mfma_f32_16x16x32_bf16(bhx.s, afr[8], a1, 0, 0, 0);
      a1 = __builtin_amdgcn_mfma_f32_16x16x32_bf16(blx.s, afr[8], a1, 0, 0, 0);
      if (l < 16) rpart[ktx * 128 + rtx * 16 + l] = a1[0];
    }
    __syncthreads();
    if (tid < 128) {
      float rs = 0.0f;
#pragma unroll
      for (int kc = 0; kc < 18; ++kc) rs += rpart[kc * 128 + tid];
      float un = C_mu - EPS_OT * __logf(rs);
      uu[tid] = un;
      float a = __expf(fminf(fmaxf(un * INV_EPS, -80.f), 80.f));
      unsigned int hi = f2bf(a);
      au_hs[tid] = (ushort_t)hi;
      au_ls[tid] = (ushort_t)f2bf(a - bf2f(hi));
    } else if (tid < 704) {
      const int j = tid - 128;
      const unsigned int tg = (unsigned int)(t + 1);
      unsigned long long p0;
      for (;;) {
        p0 = __hip_atomic_load(&prP[par * 576 + j], __ATOMIC_RELAXED, __HIP_MEMORY_SCOPE_AGENT);
        if ((unsigned int)(p0 >> 32) == tg) break;
        __builtin_amdgcn_s_sleep(1);
      }
      float tot = cso[j] + __uint_as_float((unsigned int)p0);
      float vn = C_nu - EPS_OT * __logf(tot);
      vv[j] = vn;
      float bb = __expf(fminf(fmaxf(vn * INV_EPS, -80.f), 80.f));
      unsigned int hi = f2bf(bb);
      bv_hs[j] = (ushort_t)hi;
      bv_ls[j] = (ushort_t)f2bf(bb - bf2f(hi));
    }
    __syncthreads();
  }
  if (tid < 128) gA[(size_t)s * 256 + rh * 128 + tid] = uu[tid] * INV_EPS;
  if (rh == 0 && tid < 576) gB[(size_t)s * 576 + tid] = vv[tid] * INV_EPS + 11.9012851f;  // +ln(147456)
}

// ---------- scorev: out(bf16) = score @ V via MFMA (hi/lo P, bf16 V) ----------
__global__ __launch_bounds__(256) void scorev2_k(const ushort_t* __restrict__ E,
                                                 const ushort_t* __restrict__ vt,
                                                 const float* __restrict__ gA,
                                                 const float* __restrict__ gB,
                                                 ushort_t* __restrict__ Y) {
  __shared__ float gBs[576];
  const int s = blockIdx.x, i0 = blockIdx.y << 6;
  const int tid = threadIdx.x;
  const int w = tid >> 6, l = tid & 63, li = l & 15, lg = l >> 4;
  for (int j = tid; j < 576; j += 256) gBs[j] = gB[(size_t)s * 576 + j];
  const float ga = gA[(size_t)s * 256 + i0 + 16 * w + li];
  const ushort_t* Erow = E + (size_t)s * 147456 + (size_t)(i0 + 16 * w + li) * 576;
  f32x4 acc[4] = {};
  __syncthreads();
  for (int kst = 0; kst < 18; ++kst) {
    const int jb = kst * 32 + 8 * lg;
    Pk eu; eu.u = *(const uint4*)(Erow + jb);
    float pv[8], pl8[8];
#pragma unroll
    for (int jj = 0; jj < 8; ++jj) {
      unsigned int us = (unsigned int)(unsigned short)eu.s[jj];
      float e = bf2f(us);
      float le = __logf(e);
      pv[jj] = (1.0f + EPS_OT * le) * __expf(le + ga + gBs[jb + jj]);
    }
    Pk ph, pl;
#pragma unroll
    for (int jj = 0; jj < 8; ++jj) {
      unsigned int h = f2bf(pv[jj]);
      ((unsigned short*)&ph.s)[jj] = (unsigned short)h;
      pl8[jj] = pv[jj] - bf2f(h);
    }
#pragma unroll
    for (int jj = 0; jj < 8; ++jj)
      ((unsigned short*)&pl.s)[jj] = (unsigned short)f2bf(pl8[jj]);
#pragma unroll
    for (int nt = 0; nt < 4; ++nt) {
      Pk vf; vf.u = *(const uint4*)(vt + ((size_t)s * 64 + nt * 16 + li) * 576 + jb);
      acc[nt] = __builtin_amdgcn_mfma_f32_16x16x32_bf16(ph.s, vf.s, acc[nt], 0, 0, 0);
      acc[nt] = __builtin_amdgcn_mfma_f32_16x16x32_bf16(pl.s, vf.s, acc[nt], 0, 0, 0);
    }
  }
  const int b = s >> 3, h = s & 7;
#pragma unroll
  for (int nt = 0; nt < 4; ++nt)
#pragma unroll
    for (int reg = 0; reg < 4; ++reg)
      Y[((size_t)(b * 256 + i0 + 16 * w + 4 * lg + reg) << 9) + (h << 6) + nt * 16 + li] =
          (ushort_t)f2bf(acc[nt][reg]);
}

// ------------------------- final row l2norm (plain division) -------------------------
__global__ __launch_bounds__(256) void rownorm_k(const float* __restrict__ X,
                                                 float* __restrict__ out) {
  const size_t row = blockIdx.x;
  const int tid = threadIdx.x;
  float x0 = X[(row << 9) + tid], x1 = X[(row << 9) + 256 + tid];
  float st = fmaf(x0, x0, x1 * x1);
#pragma unroll
  for (int off = 32; off; off >>= 1) st += __shfl_xor(st, off, 64);
  __shared__ float ps[4];
  if ((tid & 63) == 0) ps[tid >> 6] = st;
  __syncthreads();
  const float inv = 1.0f / sqrtf(ps[0] + ps[1] + ps[2] + ps[3]);
  out[(row << 9) + tid] = x0 * inv;
  out[(row << 9) + 256 + tid] = x1 * inv;
}

extern "C" void kernel_launch(void* const* d_in, const int* in_sizes, int n_in,
                              void* d_out, int out_size, void* d_ws, size_t ws_size,
                              hipStream_t stream) {
  const float* F_t = (const float*)d_in[0];
  const float* F_s = (const float*)d_in[1];
  const float* Wq = (const float*)d_in[2];
  const float* bq = (const float*)d_in[3];
  const float* Wk = (const float*)d_in[4];
  const float* bk = (const float*)d_in[5];
  const float* Wv = (const float*)d_in[6];
  const float* bvb = (const float*)d_in[7];
  const float* Wp = (const float*)d_in[8];
  const float* bp = (const float*)d_in[9];
  float* out = (float*)d_out;

  ushort_t* u0 = (ushort_t*)d_ws;
  ushort_t* Fth = u0;                      //  2,097,152
  ushort_t* Ftl = Fth + 2097152;
  ushort_t* Fsh = Ftl + 2097152;           //  4,718,592
  ushort_t* Fsl = Fsh + 4718592;
  ushort_t* Wqh = Fsl + 4718592;           //  262,144 each
  ushort_t* Wql = Wqh + 262144;
  ushort_t* Wkh = Wql + 262144;
  ushort_t* Wkl = Wkh + 262144;
  ushort_t* Wvh = Wkl + 262144;
  ushort_t* Wvl = Wvh + 262144;
  ushort_t* Wph = Wvl + 262144;
  ushort_t* qh = Wph + 262144;             //  2,097,152
  ushort_t* ql = qh + 2097152;
  ushort_t* kh = ql + 2097152;             //  4,718,592
  ushort_t* kl = kh + 4718592;
  ushort_t* vt = kl + 4718592;             //  4,718,592  [128][64][576]
  ushort_t* Eb = vt + 4718592;             // 18,874,368  [128][256][576]
  ushort_t* T0b = Eb + 18874368;           //  2,097,152  (scorev out bf16)
  float* T1 = (float*)(T0b + 2097152);     //  2,097,152 f32
  float* gA = T1 + 2097152;                //  32,768
  float* gB = gA + 32768;                  //  73,728
  unsigned long long* gpart = (unsigned long long*)(gB + 73728);  // 256*1152 ull

  const float C_mu = (float)(0.05 * log(1.0 / 256.0 + 1e-8));
  const float C_nu = (float)(0.05 * log(1.0 / 576.0 + 1e-8));

  (void)hipFuncSetAttribute((const void*)sinkhorn6_k,
                            hipFuncAttributeMaxDynamicSharedMemorySize, SK_SMEM);

  pack_k<<<7680, 256, 0, stream>>>(F_t, F_s, Wq, Wk, Wv, Wp, Fth, Ftl, Fsh, Fsl,
                                   Wqh, Wql, Wkh, Wkl, Wvh, Wvl, Wph);
  gemmnorm2_k<<<dim3(64, 8), 256, 0, stream>>>(Fth, Ftl, Wqh, Wql, bq, qh, ql, 256);
  gemmnorm2_k<<<dim3(144, 8), 256, 0, stream>>>(Fsh, Fsl, Wkh, Wkl, bk, kh, kl, 576);
  gemmtrans2_k<<<dim3(144, 8), 256, 0, stream>>>(Fsh, Wvh, bvb, vt);
  simE2_k<<<dim3(128, 4, 9), 256, 0, stream>>>(qh, ql, kh, kl, Eb);
  sinkhorn6_k<<<256, 1024, SK_SMEM, stream>>>(Eb, gA, gB, gpart, C_mu, C_nu);
  scorev2_k<<<dim3(128, 4), 256, 0, stream>>>(Eb, vt, gA, gB, T0b);
  gemmplain_k<<<dim3(64, 8), 256, 0, stream>>>(T0b, Wph, bp, T1);
  rownorm_k<<<4096, 256, 0, stream>>>(T1, out);
}